// Round 5
// baseline (172.300 us; speedup 1.0000x reference)
//
#include <hip/hip_runtime.h>
#include <hip/hip_bf16.h>

// Shapes (fixed for this problem)
#define S_LEN 1024
#define D_DIM 1024
#define N_BAT 8
#define BSS   (8ull*1024ull*1024ull)   // B*S*S elements per output

using bf16x8 = __attribute__((ext_vector_type(8))) short;
using f32x4  = __attribute__((ext_vector_type(4))) float;

__device__ __forceinline__ short f2bf(float v) {
    __hip_bfloat16 h = __float2bfloat16(v);
    return *reinterpret_cast<short*>(&h);
}

__device__ __forceinline__ void gload_lds16(const void* g, void* l) {
    __builtin_amdgcn_global_load_lds(
        (const __attribute__((address_space(1))) void*)g,
        (__attribute__((address_space(3))) void*)l, 16, 0, 0);
}

// XCD-aware bijective block remap (requires nwg % 8 == 0).
// Consecutive remapped ids stay on one XCD -> L2 panel reuse.
__device__ __forceinline__ int xcd_remap_flat() {
    const int nwg  = gridDim.x * gridDim.y * gridDim.z;
    const int flat = blockIdx.x + gridDim.x * (blockIdx.y + gridDim.y * blockIdx.z);
    const int cpx  = nwg >> 3;
    return (flat & 7) * cpx + (flat >> 3);
}

// ---------------------------------------------------------------------------
// GEMM mainloop: 128x128 tile, BK=64, double-buffered LDS, 4 waves.
// T3-min schedule: STAGE(next) issued BEFORE compute(cur); one barrier/tile.
// A, Bt row-major [*][1024] bf16; Bt is the transposed operand (C=A.Bt^T).
// ---------------------------------------------------------------------------
__device__ __forceinline__ void gemm_mainloop(
    const short* __restrict__ A, const short* __restrict__ Bt,
    int brow, int bcol, short* As, short* Bs, f32x4 acc[4][4])
{
    const int tid  = threadIdx.x;
    const int lane = tid & 63;
    const int w    = tid >> 6;
    const int wr   = w >> 1, wc = w & 1;
    const int q0   = w * 4096 + lane * 16;   // byte offset base in 16KB buffer
    const int rsel = lane & 15;
    const int ksel = (lane >> 4) * 8;

#pragma unroll
    for (int m = 0; m < 4; ++m)
#pragma unroll
        for (int n = 0; n < 4; ++n) acc[m][n] = 0.0f;

    // prologue: stage K-tile 0 into buffer 0
#pragma unroll
    for (int c = 0; c < 4; ++c) {
        const int q = q0 + c * 1024;
        const int row = q >> 7;            // 128 B per 64-elem row
        const int col = (q & 127) >> 1;
        gload_lds16(A  + (size_t)(brow + row) * 1024 + col, (char*)As + q);
        gload_lds16(Bt + (size_t)(bcol + row) * 1024 + col, (char*)Bs + q);
    }
    __syncthreads();

    for (int t = 0; t < 16; ++t) {
        const int cur = t & 1;
        const short* Ac = As + cur * 8192;   // 8192 shorts = 16 KB
        const short* Bc = Bs + cur * 8192;
        if (t < 15) {                        // issue next-tile loads FIRST
            const int k0 = (t + 1) * 64;
            char* An = (char*)As + (cur ^ 1) * 16384;
            char* Bn = (char*)Bs + (cur ^ 1) * 16384;
#pragma unroll
            for (int c = 0; c < 4; ++c) {
                const int q = q0 + c * 1024;
                const int row = q >> 7;
                const int col = (q & 127) >> 1;
                gload_lds16(A  + (size_t)(brow + row) * 1024 + (k0 + col), An + q);
                gload_lds16(Bt + (size_t)(bcol + row) * 1024 + (k0 + col), Bn + q);
            }
        }
        bf16x8 af[4][2], bfr[4][2];
#pragma unroll
        for (int m = 0; m < 4; ++m) {
            const int row = wr * 64 + m * 16 + rsel;
#pragma unroll
            for (int kk = 0; kk < 2; ++kk)
                af[m][kk] = *(const bf16x8*)&Ac[row * 64 + kk * 32 + ksel];
        }
#pragma unroll
        for (int n = 0; n < 4; ++n) {
            const int row = wc * 64 + n * 16 + rsel;
#pragma unroll
            for (int kk = 0; kk < 2; ++kk)
                bfr[n][kk] = *(const bf16x8*)&Bc[row * 64 + kk * 32 + ksel];
        }
#pragma unroll
        for (int kk = 0; kk < 2; ++kk)
#pragma unroll
            for (int m = 0; m < 4; ++m)
#pragma unroll
                for (int n = 0; n < 4; ++n)
                    acc[m][n] = __builtin_amdgcn_mfma_f32_16x16x32_bf16(
                        af[m][kk], bfr[n][kk], acc[m][n], 0, 0, 0);
        __syncthreads();   // drains next-tile loads + releases buffers
    }
}

// ---------------------------------------------------------------------------
// 3a) bf16-out GEMM (M2T and t-GEMM). XCD-chunk swizzled grid.
// ---------------------------------------------------------------------------
__global__ __launch_bounds__(256) void gemm_bf16(
    const short* __restrict__ A, const short* __restrict__ Bt,
    short* __restrict__ C)
{
    __shared__ short As[2 * 8192];
    __shared__ short Bs[2 * 8192];
    const int nid = xcd_remap_flat();
    const int mx  = nid % gridDim.x;
    const int ny  = nid / gridDim.x;        // gridDim.z == 1 here
    const int brow = mx * 128, bcol = ny * 128;

    f32x4 acc[4][4];
    gemm_mainloop(A, Bt, brow, bcol, As, Bs, acc);

    const int lane = threadIdx.x & 63;
    const int w    = threadIdx.x >> 6;
    const int wr   = w >> 1, wc = w & 1;
#pragma unroll
    for (int m = 0; m < 4; ++m)
#pragma unroll
        for (int n = 0; n < 4; ++n) {
            const int colg = bcol + wc * 64 + n * 16 + (lane & 15);
#pragma unroll
            for (int r = 0; r < 4; ++r) {
                const int rowg = brow + wr * 64 + m * 16 + ((lane >> 4) * 4 + r);
                C[(size_t)rowg * 1024 + colg] = f2bf(acc[m][n][r]);
            }
        }
}

// ---------------------------------------------------------------------------
// 3b) Scores GEMM (batched): Sc[b][q][k] = (t[q].x[k] + p[q] + r[k] + c0)/512
// ---------------------------------------------------------------------------
__global__ __launch_bounds__(256) void gemm_scores(
    const short* __restrict__ Tm, const short* __restrict__ Xm,
    const float* __restrict__ p, const float* __restrict__ r2,
    const float* __restrict__ c0p, float* __restrict__ Sc)
{
    __shared__ short As[2 * 8192];
    __shared__ short Bs[2 * 8192];
    const int nid = xcd_remap_flat();
    const int mx  = nid & 7;
    const int ny  = (nid >> 3) & 7;
    const int b   = nid >> 6;               // one batch per XCD chunk
    const short* A  = Tm + (size_t)b * 1024 * 1024;
    const short* Bt = Xm + (size_t)b * 1024 * 1024;
    const float* pb = p  + (size_t)b * 1024;
    const float* rb = r2 + (size_t)b * 1024;
    float* C = Sc + (size_t)b * 1024 * 1024;
    const int brow = mx * 128, bcol = ny * 128;

    f32x4 acc[4][4];
    gemm_mainloop(A, Bt, brow, bcol, As, Bs, acc);

    const int lane = threadIdx.x & 63;
    const int w    = threadIdx.x >> 6;
    const int wr   = w >> 1, wc = w & 1;
    const float c0v = c0p[0];
#pragma unroll
    for (int m = 0; m < 4; ++m)
#pragma unroll
        for (int n = 0; n < 4; ++n) {
            const int colg = bcol + wc * 64 + n * 16 + (lane & 15);
            const float radd = rb[colg] + c0v;
#pragma unroll
            for (int r = 0; r < 4; ++r) {
                const int rowg = brow + wr * 64 + m * 16 + ((lane >> 4) * 4 + r);
                C[(size_t)rowg * 1024 + colg] =
                    (acc[m][n][r] + pb[rowg] + radd) * 0.001953125f; // /512
            }
        }
}

// ---------------------------------------------------------------------------
// 0a) Bias GEMV stage 1: partial sums of u = Wq^T bk, v = Wk^T bq.
// ---------------------------------------------------------------------------
__global__ __launch_bounds__(256) void bias_gemv1(
    const float* __restrict__ Wq, const float* __restrict__ Wk,
    const float* __restrict__ bk, const float* __restrict__ bq,
    float* __restrict__ pu, float* __restrict__ pv)
{
    __shared__ float su[8][128];
    __shared__ float sv[8][128];
    const int tx = threadIdx.x & 31;
    const int ty = threadIdx.x >> 5;
    const int colBase = blockIdx.x * 128;
    const int rowBase = blockIdx.y * 64;
    const int i = colBase + tx * 4;
    float4 au = {0,0,0,0}, av = {0,0,0,0};
#pragma unroll
    for (int jj = 0; jj < 8; ++jj) {
        const int j = rowBase + ty + jj * 8;
        const float bkv = bk[j], bqv = bq[j];
        const float4 wq = *(const float4*)&Wq[(size_t)j * 1024 + i];
        const float4 wk = *(const float4*)&Wk[(size_t)j * 1024 + i];
        au.x += wq.x * bkv; au.y += wq.y * bkv; au.z += wq.z * bkv; au.w += wq.w * bkv;
        av.x += wk.x * bqv; av.y += wk.y * bqv; av.z += wk.z * bqv; av.w += wk.w * bqv;
    }
    ((float4*)su[ty])[tx] = au;
    ((float4*)sv[ty])[tx] = av;
    __syncthreads();
    if (ty == 0) {
        float4 s1 = ((float4*)su[0])[tx];
        float4 s2 = ((float4*)sv[0])[tx];
#pragma unroll
        for (int k = 1; k < 8; ++k) {
            const float4 t1 = ((float4*)su[k])[tx];
            const float4 t2 = ((float4*)sv[k])[tx];
            s1.x += t1.x; s1.y += t1.y; s1.z += t1.z; s1.w += t1.w;
            s2.x += t2.x; s2.y += t2.y; s2.z += t2.z; s2.w += t2.w;
        }
        ((float4*)&pu[(size_t)blockIdx.y * 1024 + colBase])[tx] = s1;
        ((float4*)&pv[(size_t)blockIdx.y * 1024 + colBase])[tx] = s2;
    }
}

// ---------------------------------------------------------------------------
// 0b) Bias GEMV stage 2: reduce 16 partials per column; also c0 = bq.bk
// ---------------------------------------------------------------------------
__global__ __launch_bounds__(256) void bias_gemv2(
    const float* __restrict__ pu, const float* __restrict__ pv,
    const float* __restrict__ bk, const float* __restrict__ bq,
    float* __restrict__ u, float* __restrict__ v, float* __restrict__ c0)
{
    __shared__ float sh[4];
    const int i = blockIdx.x * 256 + threadIdx.x;
    float su = 0.0f, sv = 0.0f;
#pragma unroll
    for (int k = 0; k < 16; ++k) {
        su += pu[k * 1024 + i];
        sv += pv[k * 1024 + i];
    }
    u[i] = su;
    v[i] = sv;
    if (blockIdx.x == 0) {
        const int t = threadIdx.x;
        const float4 a = ((const float4*)bq)[t];
        const float4 b = ((const float4*)bk)[t];
        float s = a.x*b.x + a.y*b.y + a.z*b.z + a.w*b.w;
        for (int off = 32; off > 0; off >>= 1) s += __shfl_down(s, off);
        const int lane = t & 63, w = t >> 6;
        if (lane == 0) sh[w] = s;
        __syncthreads();
        if (t == 0) c0[0] = sh[0] + sh[1] + sh[2] + sh[3];
    }
}

// ---------------------------------------------------------------------------
// 1) LayerNorm -> bf16; also emits p[row] = y.u and r2[row] = y.v
// ---------------------------------------------------------------------------
__global__ __launch_bounds__(256) void ln_kernel(
    const float* __restrict__ X, const float* __restrict__ gamma,
    const float* __restrict__ beta, const float* __restrict__ u,
    const float* __restrict__ v2, short* __restrict__ Y,
    float* __restrict__ p, float* __restrict__ r2)
{
    __shared__ float sh[16];
    const size_t row = blockIdx.x;
    const int t = threadIdx.x;
    float4 v = ((const float4*)(X + row * 1024))[t];
    float s  = v.x + v.y + v.z + v.w;
    float ss = v.x*v.x + v.y*v.y + v.z*v.z + v.w*v.w;
    for (int off = 32; off > 0; off >>= 1) {
        s  += __shfl_down(s, off);
        ss += __shfl_down(ss, off);
    }
    const int lane = t & 63, w = t >> 6;
    if (lane == 0) { sh[w] = s; sh[4 + w] = ss; }
    __syncthreads();
    if (t == 0) {
        float S  = sh[0] + sh[1] + sh[2] + sh[3];
        float SS = sh[4] + sh[5] + sh[6] + sh[7];
        float mu = S * (1.0f / 1024.0f);
        float var = fmaxf((SS - S * mu) * (1.0f / 1023.0f), 0.0f);
        sh[0] = mu;
        sh[1] = 1.0f / (sqrtf(var) + 1e-6f);
    }
    __syncthreads();
    const float mu = sh[0], inv = sh[1];
    float4 g  = ((const float4*)gamma)[t];
    float4 be = ((const float4*)beta)[t];
    float y0 = g.x * (v.x - mu) * inv + be.x;
    float y1 = g.y * (v.y - mu) * inv + be.y;
    float y2 = g.z * (v.z - mu) * inv + be.z;
    float y3 = g.w * (v.w - mu) * inv + be.w;
    short4 o;
    o.x = f2bf(y0); o.y = f2bf(y1); o.z = f2bf(y2); o.w = f2bf(y3);
    ((short4*)(Y + row * 1024))[t] = o;
    float4 uu = ((const float4*)u)[t];
    float4 vv = ((const float4*)v2)[t];
    float dp = y0*uu.x + y1*uu.y + y2*uu.z + y3*uu.w;
    float dr = y0*vv.x + y1*vv.y + y2*vv.z + y3*vv.w;
    for (int off = 32; off > 0; off >>= 1) {
        dp += __shfl_down(dp, off);
        dr += __shfl_down(dr, off);
    }
    if (lane == 0) { sh[8 + w] = dp; sh[12 + w] = dr; }
    __syncthreads();
    if (t == 0) {
        p[row]  = sh[8] + sh[9] + sh[10] + sh[11];
        r2[row] = sh[12] + sh[13] + sh[14] + sh[15];
    }
}

// ---------------------------------------------------------------------------
// 2) Transpose + convert Wq, Wk (f32 [D][D]) -> bf16 transposed copies
// ---------------------------------------------------------------------------
__global__ __launch_bounds__(256) void cvt_t_kernel(
    const float* __restrict__ Wq, const float* __restrict__ Wk,
    short* __restrict__ wqt, short* __restrict__ wkt)
{
    __shared__ float T[32][33];
    const float* src = blockIdx.z ? Wk : Wq;
    short* dst = blockIdx.z ? wkt : wqt;
    const int bi = blockIdx.x * 32, bj = blockIdx.y * 32;
    const int c = threadIdx.x & 31, r0 = threadIdx.x >> 5;
#pragma unroll
    for (int rr = 0; rr < 4; ++rr) {
        const int r = r0 + rr * 8;
        T[r][c] = src[(size_t)(bi + r) * 1024 + bj + c];
    }
    __syncthreads();
#pragma unroll
    for (int rr = 0; rr < 4; ++rr) {
        const int r = r0 + rr * 8;
        dst[(size_t)(bj + r) * 1024 + bi + c] = f2bf(T[c][r]);
    }
}

// ---------------------------------------------------------------------------
// 5) Masked row softmax: block per (b,q) row
// ---------------------------------------------------------------------------
__global__ __launch_bounds__(256) void softmax_kernel(
    const float* __restrict__ Sc, const int* __restrict__ adj,
    float* __restrict__ At)
{
    __shared__ float sh[4];
    const size_t row = blockIdx.x;
    const int t = threadIdx.x;
    const float4 sv = ((const float4*)(Sc + row * 1024))[t];
    const int4   av = ((const int4*)(adj + row * 1024))[t];
    float m = -3.0e38f;
    if (av.x) m = fmaxf(m, sv.x);
    if (av.y) m = fmaxf(m, sv.y);
    if (av.z) m = fmaxf(m, sv.z);
    if (av.w) m = fmaxf(m, sv.w);
    for (int off = 32; off > 0; off >>= 1) m = fmaxf(m, __shfl_down(m, off));
    const int lane = t & 63, w = t >> 6;
    if (lane == 0) sh[w] = m;
    __syncthreads();
    const float M = fmaxf(fmaxf(sh[0], sh[1]), fmaxf(sh[2], sh[3]));
    __syncthreads();
    float e0 = av.x ? expf(sv.x - M) : 0.0f;
    float e1 = av.y ? expf(sv.y - M) : 0.0f;
    float e2 = av.z ? expf(sv.z - M) : 0.0f;
    float e3 = av.w ? expf(sv.w - M) : 0.0f;
    float s = e0 + e1 + e2 + e3;
    for (int off = 32; off > 0; off >>= 1) s += __shfl_down(s, off);
    if (lane == 0) sh[w] = s;
    __syncthreads();
    const float Sm = sh[0] + sh[1] + sh[2] + sh[3];
    float4 o;
    if (Sm > 0.0f) {
        const float inv = 1.0f / Sm;
        o.x = e0 * inv; o.y = e1 * inv; o.z = e2 * inv; o.w = e3 * inv;
    } else {
        o.x = o.y = o.z = o.w = 1.0f / 1024.0f;
    }
    ((float4*)(At + row * 1024))[t] = o;
}

// ---------------------------------------------------------------------------
// 6) Prefix sums of L[k]=log(na[k,k+1]+1e-9) per batch (f64 scan in LDS)
// ---------------------------------------------------------------------------
__global__ __launch_bounds__(1024) void cum2_kernel(
    const float* __restrict__ At, const float* __restrict__ prior_p,
    double* __restrict__ cum)
{
    __shared__ double sh[1024];
    const int b = blockIdx.x;
    const int t = threadIdx.x;
    const float prior = *prior_p;
    const float om = 1.0f - prior;
    const float* attn = At + (size_t)b * 1024 * 1024;
    double v = 0.0;
    if (t >= 1) {
        const int k = t - 1;
        const float a1 = attn[(size_t)k * 1024 + (k + 1)];
        const float a2 = attn[(size_t)(k + 1) * 1024 + k];
        const float na = prior + om * sqrtf(a1 * a2 + 1e-9f);
        v = (double)logf(na + 1e-9f);
    }
    sh[t] = v;
    __syncthreads();
#pragma unroll
    for (int off = 1; off < 1024; off <<= 1) {
        const double add = (t >= off) ? sh[t - off] : 0.0;
        __syncthreads();
        sh[t] += add;
        __syncthreads();
    }
    cum[b * 1024 + t] = sh[t];
}

// ---------------------------------------------------------------------------
// 7) Fused na (in place) + g_attn fill. 32x32 tile-pair per block.
// ---------------------------------------------------------------------------
__global__ __launch_bounds__(256) void na_g_kernel(
    float* __restrict__ At, const float* __restrict__ prior_p,
    const double* __restrict__ cum, float* __restrict__ G)
{
    const int ti = blockIdx.x >> 5, tj = blockIdx.x & 31;
    if (tj < ti) return;
    const int b = blockIdx.y;
    const float prior = *prior_p;
    const float om = 1.0f - prior;
    float* base = At + (size_t)b * 1024 * 1024;
    float* gb   = G  + (size_t)b * 1024 * 1024;
    const double* cb = cum + (size_t)b * 1024;
    __shared__ float T1[32][33];
    __shared__ float T2[32][33];
    const int c = threadIdx.x & 31, r0 = threadIdx.x >> 5;
#pragma unroll
    for (int rr = 0; rr < 4; ++rr) {
        const int r = r0 + rr * 8;
        T1[r][c] = base[(size_t)(ti * 32 + r) * 1024 + tj * 32 + c];
        T2[r][c] = base[(size_t)(tj * 32 + r) * 1024 + ti * 32 + c];
    }
    __syncthreads();
#pragma unroll
    for (int rr = 0; rr < 4; ++rr) {
        const int r = r0 + rr * 8;
        const int R1 = ti * 32 + r, C1 = tj * 32 + c;
        const float na1 = prior + om * sqrtf(T1[r][c] * T2[c][r] + 1e-9f);
        base[(size_t)R1 * 1024 + C1] = na1;
        float g1;
        if (R1 == C1) g1 = na1;
        else {
            const int lo = min(R1, C1), hi = max(R1, C1);
            g1 = expf((float)(cb[hi] - cb[lo])) + 1e-9f;
        }
        gb[(size_t)R1 * 1024 + C1] = g1;
        const int R2 = tj * 32 + r, C2 = ti * 32 + c;
        const float na2 = prior + om * sqrtf(T2[r][c] * T1[c][r] + 1e-9f);
        base[(size_t)R2 * 1024 + C2] = na2;
        float g2;
        if (R2 == C2) g2 = na2;
        else {
            const int lo = min(R2, C2), hi = max(R2, C2);
            g2 = expf((float)(cb[hi] - cb[lo])) + 1e-9f;
        }
        gb[(size_t)R2 * 1024 + C2] = g2;
    }
}

// ---------------------------------------------------------------------------
extern "C" void kernel_launch(void* const* d_in, const int* in_sizes, int n_in,
                              void* d_out, int out_size, void* d_ws, size_t ws_size,
                              hipStream_t stream)
{
    const float* context = (const float*)d_in[0];
    // d_in[1] = eos_mask (unused by reference)
    const float* prior   = (const float*)d_in[2];
    const int*   adj     = (const int*)d_in[3];
    const float* Wk      = (const float*)d_in[4];
    const float* bk      = (const float*)d_in[5];
    const float* Wq      = (const float*)d_in[6];
    const float* bq      = (const float*)d_in[7];
    const float* gamma   = (const float*)d_in[8];
    const float* beta    = (const float*)d_in[9];

    float* out   = (float*)d_out;
    float* gout  = out;          // first output: g_attn (scores scratch first)
    float* naout = out + BSS;    // second output: neibor_attn (attn in-place)

    // workspace layout (~39 MB)
    char* ws = (char*)d_ws;
    short*  xb   = (short*)(ws);                        // 16 MB  x (bf16)
    short*  wqt  = (short*)(ws + (16ull << 20));        //  2 MB  Wq^T (bf16)
    short*  wkt  = (short*)(ws + (18ull << 20));        //  2 MB  Wk^T (bf16)
    short*  m2t  = (short*)(ws + (20ull << 20));        //  2 MB  (Wq^T Wk)^T
    short*  tb   = (short*)(ws + (22ull << 20));        // 16 MB  t = x@M2
    double* cumd = (double*)(ws + (38ull << 20));       // 64 KB
    float*  uvec = (float*)(ws + (38ull << 20) + (1ull << 16)); // 4 KB
    float*  vvec = uvec + 1024;                         // 4 KB
    float*  c0   = vvec + 1024;                         // 4 B (padded)
    float*  pvec = c0 + 64;                             // 32 KB (8192 f32)
    float*  rvec = pvec + 8192;                         // 32 KB
    float*  pu   = rvec + 8192;                         // 64 KB (16x1024)
    float*  pv   = pu + 16384;                          // 64 KB

    bias_gemv1<<<dim3(8, 16), 256, 0, stream>>>(Wq, Wk, bk, bq, pu, pv);
    bias_gemv2<<<4, 256, 0, stream>>>(pu, pv, bk, bq, uvec, vvec, c0);
    ln_kernel<<<8192, 256, 0, stream>>>(context, gamma, beta, uvec, vvec,
                                        xb, pvec, rvec);
    cvt_t_kernel<<<dim3(32, 32, 2), 256, 0, stream>>>(Wq, Wk, wqt, wkt);
    // M2T[j][i] = sum_d Wkt[j][d] * Wqt[i][d]  ( = (Wq^T Wk)[i][j] )
    gemm_bf16<<<dim3(8, 8), 256, 0, stream>>>(wkt, wqt, m2t);
    // t[q][j] = sum_i xb[q][i] * M2T[j][i]
    gemm_bf16<<<dim3(64, 8), 256, 0, stream>>>(xb, m2t, tb);
    // scores[b][q][k] = (t[q].x[k] + p[q] + r[k] + c0) / 512
    gemm_scores<<<dim3(8, 8, 8), 256, 0, stream>>>(tb, xb, pvec, rvec, c0, gout);
    softmax_kernel<<<8192, 256, 0, stream>>>(gout, adj, naout);
    cum2_kernel<<<8, 1024, 0, stream>>>(naout, prior, cumd);
    na_g_kernel<<<dim3(1024, 8), 256, 0, stream>>>(naout, prior, cumd, gout);
}

// Round 6
// 146.312 us; speedup vs baseline: 1.1776x; 1.1776x over previous
//
#include <hip/hip_runtime.h>
#include <hip/hip_bf16.h>

// Shapes (fixed for this problem)
#define S_LEN 1024
#define D_DIM 1024
#define N_BAT 8
#define BSS   (8ull*1024ull*1024ull)   // B*S*S elements per output

using bf16x8 = __attribute__((ext_vector_type(8))) short;
using f32x4  = __attribute__((ext_vector_type(4))) float;

__device__ __forceinline__ short f2bf(float v) {
    __hip_bfloat16 h = __float2bfloat16(v);
    return *reinterpret_cast<short*>(&h);
}

__device__ __forceinline__ void gload_lds16(const void* g, void* l) {
    __builtin_amdgcn_global_load_lds(
        (const __attribute__((address_space(1))) void*)g,
        (__attribute__((address_space(3))) void*)l, 16, 0, 0);
}

// XCD-aware bijective block remap (requires nwg % 8 == 0).
__device__ __forceinline__ int xcd_remap_flat() {
    const int nwg  = gridDim.x * gridDim.y * gridDim.z;
    const int flat = blockIdx.x + gridDim.x * (blockIdx.y + gridDim.y * blockIdx.z);
    const int cpx  = nwg >> 3;
    return (flat & 7) * cpx + (flat >> 3);
}

// ---------------------------------------------------------------------------
// GEMM mainloop: 128x128 tile, BK=64, double-buffered LDS, 4 waves.
// STAGE(next) issued BEFORE compute(cur); one barrier per K-tile.
// T2 XOR swizzle (rule #21): LDS dest linear; global SOURCE chunk pre-swizzled
// with byte^((row&7)<<4); ds_read applies the same XOR. 16 lanes of a
// fragment read spread over 8 bank-bases -> 2-way aliasing (free).
// ---------------------------------------------------------------------------
__device__ __forceinline__ void gemm_mainloop(
    const short* __restrict__ A, const short* __restrict__ Bt,
    int brow, int bcol, short* As, short* Bs, f32x4 acc[4][4])
{
    const int tid  = threadIdx.x;
    const int lane = tid & 63;
    const int w    = tid >> 6;
    const int wr   = w >> 1, wc = w & 1;
    const int q0   = w * 4096 + lane * 16;   // linear byte offset in 16KB buffer
    const int rsel = lane & 15;
    const int kb   = (lane >> 4) * 16;       // byte offset of 16B k-chunk

#pragma unroll
    for (int m = 0; m < 4; ++m)
#pragma unroll
        for (int n = 0; n < 4; ++n) acc[m][n] = 0.0f;

    // prologue: stage K-tile 0 into buffer 0 (swizzled source)
#pragma unroll
    for (int c = 0; c < 4; ++c) {
        const int q    = q0 + c * 1024;
        const int row  = q >> 7;                           // 128 B per 64-elem row
        const int colb = (q & 127) ^ ((row & 7) << 4);     // swizzled src bytes
        gload_lds16((const char*)(A  + (size_t)(brow + row) * 1024) + colb,
                    (char*)As + q);
        gload_lds16((const char*)(Bt + (size_t)(bcol + row) * 1024) + colb,
                    (char*)Bs + q);
    }
    __syncthreads();

    for (int t = 0; t < 16; ++t) {
        const int cur = t & 1;
        const char* Ac = (const char*)As + cur * 16384;
        const char* Bc = (const char*)Bs + cur * 16384;
        if (t < 15) {                        // issue next-tile loads FIRST
            const int k0 = (t + 1) * 64;
            char* An = (char*)As + (cur ^ 1) * 16384;
            char* Bn = (char*)Bs + (cur ^ 1) * 16384;
#pragma unroll
            for (int c = 0; c < 4; ++c) {
                const int q    = q0 + c * 1024;
                const int row  = q >> 7;
                const int colb = (q & 127) ^ ((row & 7) << 4);
                gload_lds16((const char*)(A  + (size_t)(brow + row) * 1024 + k0) + colb,
                            An + q);
                gload_lds16((const char*)(Bt + (size_t)(bcol + row) * 1024 + k0) + colb,
                            Bn + q);
            }
        }
        bf16x8 af[4][2], bfr[4][2];
#pragma unroll
        for (int m = 0; m < 4; ++m) {
            const int row = wr * 64 + m * 16 + rsel;
            const int sw  = (row & 7) << 4;
#pragma unroll
            for (int kk = 0; kk < 2; ++kk)
                af[m][kk] = *(const bf16x8*)&Ac[row * 128 + ((kk * 64 + kb) ^ sw)];
        }
#pragma unroll
        for (int n = 0; n < 4; ++n) {
            const int row = wc * 64 + n * 16 + rsel;
            const int sw  = (row & 7) << 4;
#pragma unroll
            for (int kk = 0; kk < 2; ++kk)
                bfr[n][kk] = *(const bf16x8*)&Bc[row * 128 + ((kk * 64 + kb) ^ sw)];
        }
#pragma unroll
        for (int kk = 0; kk < 2; ++kk)
#pragma unroll
            for (int m = 0; m < 4; ++m)
#pragma unroll
                for (int n = 0; n < 4; ++n)
                    acc[m][n] = __builtin_amdgcn_mfma_f32_16x16x32_bf16(
                        af[m][kk], bfr[n][kk], acc[m][n], 0, 0, 0);
        __syncthreads();   // drains next-tile loads + releases buffers
    }
}

// ---------------------------------------------------------------------------
// 3a) bf16-out GEMM (M2T and t-GEMM). XCD-chunk swizzled grid.
// ---------------------------------------------------------------------------
__global__ __launch_bounds__(256) void gemm_bf16(
    const short* __restrict__ A, const short* __restrict__ Bt,
    short* __restrict__ C)
{
    __shared__ short As[2 * 8192];
    __shared__ short Bs[2 * 8192];
    const int nid = xcd_remap_flat();
    const int mx  = nid % gridDim.x;
    const int ny  = nid / gridDim.x;        // gridDim.z == 1 here
    const int brow = mx * 128, bcol = ny * 128;

    f32x4 acc[4][4];
    gemm_mainloop(A, Bt, brow, bcol, As, Bs, acc);

    const int lane = threadIdx.x & 63;
    const int w    = threadIdx.x >> 6;
    const int wr   = w >> 1, wc = w & 1;
#pragma unroll
    for (int m = 0; m < 4; ++m)
#pragma unroll
        for (int n = 0; n < 4; ++n) {
            const int colg = bcol + wc * 64 + n * 16 + (lane & 15);
#pragma unroll
            for (int r = 0; r < 4; ++r) {
                const int rowg = brow + wr * 64 + m * 16 + ((lane >> 4) * 4 + r);
                C[(size_t)rowg * 1024 + colg] = f2bf(acc[m][n][r]);
            }
        }
}

// ---------------------------------------------------------------------------
// 3b) Scores GEMM (batched): Sc[b][q][k] = (t[q].x[k] + p[q] + r[k] + c0)/512
// ---------------------------------------------------------------------------
__global__ __launch_bounds__(256) void gemm_scores(
    const short* __restrict__ Tm, const short* __restrict__ Xm,
    const float* __restrict__ p, const float* __restrict__ r2,
    const float* __restrict__ c0p, float* __restrict__ Sc)
{
    __shared__ short As[2 * 8192];
    __shared__ short Bs[2 * 8192];
    const int nid = xcd_remap_flat();
    const int mx  = nid & 7;
    const int ny  = (nid >> 3) & 7;
    const int b   = nid >> 6;               // one batch per XCD chunk
    const short* A  = Tm + (size_t)b * 1024 * 1024;
    const short* Bt = Xm + (size_t)b * 1024 * 1024;
    const float* pb = p  + (size_t)b * 1024;
    const float* rb = r2 + (size_t)b * 1024;
    float* C = Sc + (size_t)b * 1024 * 1024;
    const int brow = mx * 128, bcol = ny * 128;

    f32x4 acc[4][4];
    gemm_mainloop(A, Bt, brow, bcol, As, Bs, acc);

    const int lane = threadIdx.x & 63;
    const int w    = threadIdx.x >> 6;
    const int wr   = w >> 1, wc = w & 1;
    const float c0v = c0p[0];
#pragma unroll
    for (int m = 0; m < 4; ++m)
#pragma unroll
        for (int n = 0; n < 4; ++n) {
            const int colg = bcol + wc * 64 + n * 16 + (lane & 15);
            const float radd = rb[colg] + c0v;
#pragma unroll
            for (int r = 0; r < 4; ++r) {
                const int rowg = brow + wr * 64 + m * 16 + ((lane >> 4) * 4 + r);
                C[(size_t)rowg * 1024 + colg] =
                    (acc[m][n][r] + pb[rowg] + radd) * 0.001953125f; // /512
            }
        }
}

// ---------------------------------------------------------------------------
// 0a) Bias GEMV stage 1: partial sums of u = Wq^T bk, v = Wk^T bq.
// ---------------------------------------------------------------------------
__global__ __launch_bounds__(256) void bias_gemv1(
    const float* __restrict__ Wq, const float* __restrict__ Wk,
    const float* __restrict__ bk, const float* __restrict__ bq,
    float* __restrict__ pu, float* __restrict__ pv)
{
    __shared__ float su[8][128];
    __shared__ float sv[8][128];
    const int tx = threadIdx.x & 31;
    const int ty = threadIdx.x >> 5;
    const int colBase = blockIdx.x * 128;
    const int rowBase = blockIdx.y * 64;
    const int i = colBase + tx * 4;
    float4 au = {0,0,0,0}, av = {0,0,0,0};
#pragma unroll
    for (int jj = 0; jj < 8; ++jj) {
        const int j = rowBase + ty + jj * 8;
        const float bkv = bk[j], bqv = bq[j];
        const float4 wq = *(const float4*)&Wq[(size_t)j * 1024 + i];
        const float4 wk = *(const float4*)&Wk[(size_t)j * 1024 + i];
        au.x += wq.x * bkv; au.y += wq.y * bkv; au.z += wq.z * bkv; au.w += wq.w * bkv;
        av.x += wk.x * bqv; av.y += wk.y * bqv; av.z += wk.z * bqv; av.w += wk.w * bqv;
    }
    ((float4*)su[ty])[tx] = au;
    ((float4*)sv[ty])[tx] = av;
    __syncthreads();
    if (ty == 0) {
        float4 s1 = ((float4*)su[0])[tx];
        float4 s2 = ((float4*)sv[0])[tx];
#pragma unroll
        for (int k = 1; k < 8; ++k) {
            const float4 t1 = ((float4*)su[k])[tx];
            const float4 t2 = ((float4*)sv[k])[tx];
            s1.x += t1.x; s1.y += t1.y; s1.z += t1.z; s1.w += t1.w;
            s2.x += t2.x; s2.y += t2.y; s2.z += t2.z; s2.w += t2.w;
        }
        ((float4*)&pu[(size_t)blockIdx.y * 1024 + colBase])[tx] = s1;
        ((float4*)&pv[(size_t)blockIdx.y * 1024 + colBase])[tx] = s2;
    }
}

// ---------------------------------------------------------------------------
// 0b) Bias GEMV stage 2: reduce 16 partials per column; also c0 = bq.bk
// ---------------------------------------------------------------------------
__global__ __launch_bounds__(256) void bias_gemv2(
    const float* __restrict__ pu, const float* __restrict__ pv,
    const float* __restrict__ bk, const float* __restrict__ bq,
    float* __restrict__ u, float* __restrict__ v, float* __restrict__ c0)
{
    __shared__ float sh[4];
    const int i = blockIdx.x * 256 + threadIdx.x;
    float su = 0.0f, sv = 0.0f;
#pragma unroll
    for (int k = 0; k < 16; ++k) {
        su += pu[k * 1024 + i];
        sv += pv[k * 1024 + i];
    }
    u[i] = su;
    v[i] = sv;
    if (blockIdx.x == 0) {
        const int t = threadIdx.x;
        const float4 a = ((const float4*)bq)[t];
        const float4 b = ((const float4*)bk)[t];
        float s = a.x*b.x + a.y*b.y + a.z*b.z + a.w*b.w;
        for (int off = 32; off > 0; off >>= 1) s += __shfl_down(s, off);
        const int lane = t & 63, w = t >> 6;
        if (lane == 0) sh[w] = s;
        __syncthreads();
        if (t == 0) c0[0] = sh[0] + sh[1] + sh[2] + sh[3];
    }
}

// ---------------------------------------------------------------------------
// 1) LayerNorm -> bf16; also emits p[row] = y.u and r2[row] = y.v
// ---------------------------------------------------------------------------
__global__ __launch_bounds__(256) void ln_kernel(
    const float* __restrict__ X, const float* __restrict__ gamma,
    const float* __restrict__ beta, const float* __restrict__ u,
    const float* __restrict__ v2, short* __restrict__ Y,
    float* __restrict__ p, float* __restrict__ r2)
{
    __shared__ float sh[16];
    const size_t row = blockIdx.x;
    const int t = threadIdx.x;
    float4 v = ((const float4*)(X + row * 1024))[t];
    float s  = v.x + v.y + v.z + v.w;
    float ss = v.x*v.x + v.y*v.y + v.z*v.z + v.w*v.w;
    for (int off = 32; off > 0; off >>= 1) {
        s  += __shfl_down(s, off);
        ss += __shfl_down(ss, off);
    }
    const int lane = t & 63, w = t >> 6;
    if (lane == 0) { sh[w] = s; sh[4 + w] = ss; }
    __syncthreads();
    if (t == 0) {
        float S  = sh[0] + sh[1] + sh[2] + sh[3];
        float SS = sh[4] + sh[5] + sh[6] + sh[7];
        float mu = S * (1.0f / 1024.0f);
        float var = fmaxf((SS - S * mu) * (1.0f / 1023.0f), 0.0f);
        sh[0] = mu;
        sh[1] = 1.0f / (sqrtf(var) + 1e-6f);
    }
    __syncthreads();
    const float mu = sh[0], inv = sh[1];
    float4 g  = ((const float4*)gamma)[t];
    float4 be = ((const float4*)beta)[t];
    float y0 = g.x * (v.x - mu) * inv + be.x;
    float y1 = g.y * (v.y - mu) * inv + be.y;
    float y2 = g.z * (v.z - mu) * inv + be.z;
    float y3 = g.w * (v.w - mu) * inv + be.w;
    short4 o;
    o.x = f2bf(y0); o.y = f2bf(y1); o.z = f2bf(y2); o.w = f2bf(y3);
    ((short4*)(Y + row * 1024))[t] = o;
    float4 uu = ((const float4*)u)[t];
    float4 vv = ((const float4*)v2)[t];
    float dp = y0*uu.x + y1*uu.y + y2*uu.z + y3*uu.w;
    float dr = y0*vv.x + y1*vv.y + y2*vv.z + y3*vv.w;
    for (int off = 32; off > 0; off >>= 1) {
        dp += __shfl_down(dp, off);
        dr += __shfl_down(dr, off);
    }
    if (lane == 0) { sh[8 + w] = dp; sh[12 + w] = dr; }
    __syncthreads();
    if (t == 0) {
        p[row]  = sh[8] + sh[9] + sh[10] + sh[11];
        r2[row] = sh[12] + sh[13] + sh[14] + sh[15];
    }
}

// ---------------------------------------------------------------------------
// 2) Transpose + convert Wq, Wk (f32 [D][D]) -> bf16 transposed copies
// ---------------------------------------------------------------------------
__global__ __launch_bounds__(256) void cvt_t_kernel(
    const float* __restrict__ Wq, const float* __restrict__ Wk,
    short* __restrict__ wqt, short* __restrict__ wkt)
{
    __shared__ float T[32][33];
    const float* src = blockIdx.z ? Wk : Wq;
    short* dst = blockIdx.z ? wkt : wqt;
    const int bi = blockIdx.x * 32, bj = blockIdx.y * 32;
    const int c = threadIdx.x & 31, r0 = threadIdx.x >> 5;
#pragma unroll
    for (int rr = 0; rr < 4; ++rr) {
        const int r = r0 + rr * 8;
        T[r][c] = src[(size_t)(bi + r) * 1024 + bj + c];
    }
    __syncthreads();
#pragma unroll
    for (int rr = 0; rr < 4; ++rr) {
        const int r = r0 + rr * 8;
        dst[(size_t)(bj + r) * 1024 + bi + c] = f2bf(T[c][r]);
    }
}

// ---------------------------------------------------------------------------
// 5) Masked row softmax: block per (b,q) row
// ---------------------------------------------------------------------------
__global__ __launch_bounds__(256) void softmax_kernel(
    const float* __restrict__ Sc, const int* __restrict__ adj,
    float* __restrict__ At)
{
    __shared__ float sh[4];
    const size_t row = blockIdx.x;
    const int t = threadIdx.x;
    const float4 sv = ((const float4*)(Sc + row * 1024))[t];
    const int4   av = ((const int4*)(adj + row * 1024))[t];
    float m = -3.0e38f;
    if (av.x) m = fmaxf(m, sv.x);
    if (av.y) m = fmaxf(m, sv.y);
    if (av.z) m = fmaxf(m, sv.z);
    if (av.w) m = fmaxf(m, sv.w);
    for (int off = 32; off > 0; off >>= 1) m = fmaxf(m, __shfl_down(m, off));
    const int lane = t & 63, w = t >> 6;
    if (lane == 0) sh[w] = m;
    __syncthreads();
    const float M = fmaxf(fmaxf(sh[0], sh[1]), fmaxf(sh[2], sh[3]));
    __syncthreads();
    float e0 = av.x ? expf(sv.x - M) : 0.0f;
    float e1 = av.y ? expf(sv.y - M) : 0.0f;
    float e2 = av.z ? expf(sv.z - M) : 0.0f;
    float e3 = av.w ? expf(sv.w - M) : 0.0f;
    float s = e0 + e1 + e2 + e3;
    for (int off = 32; off > 0; off >>= 1) s += __shfl_down(s, off);
    if (lane == 0) sh[w] = s;
    __syncthreads();
    const float Sm = sh[0] + sh[1] + sh[2] + sh[3];
    float4 o;
    if (Sm > 0.0f) {
        const float inv = 1.0f / Sm;
        o.x = e0 * inv; o.y = e1 * inv; o.z = e2 * inv; o.w = e3 * inv;
    } else {
        o.x = o.y = o.z = o.w = 1.0f / 1024.0f;
    }
    ((float4*)(At + row * 1024))[t] = o;
}

// ---------------------------------------------------------------------------
// 6) Prefix sums of L[k]=log(na[k,k+1]+1e-9) per batch (f64 scan in LDS)
// ---------------------------------------------------------------------------
__global__ __launch_bounds__(1024) void cum2_kernel(
    const float* __restrict__ At, const float* __restrict__ prior_p,
    double* __restrict__ cum)
{
    __shared__ double sh[1024];
    const int b = blockIdx.x;
    const int t = threadIdx.x;
    const float prior = *prior_p;
    const float om = 1.0f - prior;
    const float* attn = At + (size_t)b * 1024 * 1024;
    double v = 0.0;
    if (t >= 1) {
        const int k = t - 1;
        const float a1 = attn[(size_t)k * 1024 + (k + 1)];
        const float a2 = attn[(size_t)(k + 1) * 1024 + k];
        const float na = prior + om * sqrtf(a1 * a2 + 1e-9f);
        v = (double)logf(na + 1e-9f);
    }
    sh[t] = v;
    __syncthreads();
#pragma unroll
    for (int off = 1; off < 1024; off <<= 1) {
        const double add = (t >= off) ? sh[t - off] : 0.0;
        __syncthreads();
        sh[t] += add;
        __syncthreads();
    }
    cum[b * 1024 + t] = sh[t];
}

// ---------------------------------------------------------------------------
// 7) Fused na (in place) + g_attn fill. 32x32 tile-pair per block.
// ---------------------------------------------------------------------------
__global__ __launch_bounds__(256) void na_g_kernel(
    float* __restrict__ At, const float* __restrict__ prior_p,
    const double* __restrict__ cum, float* __restrict__ G)
{
    const int ti = blockIdx.x >> 5, tj = blockIdx.x & 31;
    if (tj < ti) return;
    const int b = blockIdx.y;
    const float prior = *prior_p;
    const float om = 1.0f - prior;
    float* base = At + (size_t)b * 1024 * 1024;
    float* gb   = G  + (size_t)b * 1024 * 1024;
    const double* cb = cum + (size_t)b * 1024;
    __shared__ float T1[32][33];
    __shared__ float T2[32][33];
    const int c = threadIdx.x & 31, r0 = threadIdx.x >> 5;
#pragma unroll
    for (int rr = 0; rr < 4; ++rr) {
        const int r = r0 + rr * 8;
        T1[r][c] = base[(size_t)(ti * 32 + r) * 1024 + tj * 32 + c];
        T2[r][c] = base[(size_t)(tj * 32 + r) * 1024 + ti * 32 + c];
    }
    __syncthreads();
#pragma unroll
    for (int rr = 0; rr < 4; ++rr) {
        const int r = r0 + rr * 8;
        const int R1 = ti * 32 + r, C1 = tj * 32 + c;
        const float na1 = prior + om * sqrtf(T1[r][c] * T2[c][r] + 1e-9f);
        base[(size_t)R1 * 1024 + C1] = na1;
        float g1;
        if (R1 == C1) g1 = na1;
        else {
            const int lo = min(R1, C1), hi = max(R1, C1);
            g1 = expf((float)(cb[hi] - cb[lo])) + 1e-9f;
        }
        gb[(size_t)R1 * 1024 + C1] = g1;
        const int R2 = tj * 32 + r, C2 = ti * 32 + c;
        const float na2 = prior + om * sqrtf(T2[r][c] * T1[c][r] + 1e-9f);
        base[(size_t)R2 * 1024 + C2] = na2;
        float g2;
        if (R2 == C2) g2 = na2;
        else {
            const int lo = min(R2, C2), hi = max(R2, C2);
            g2 = expf((float)(cb[hi] - cb[lo])) + 1e-9f;
        }
        gb[(size_t)R2 * 1024 + C2] = g2;
    }
}

// ---------------------------------------------------------------------------
extern "C" void kernel_launch(void* const* d_in, const int* in_sizes, int n_in,
                              void* d_out, int out_size, void* d_ws, size_t ws_size,
                              hipStream_t stream)
{
    const float* context = (const float*)d_in[0];
    // d_in[1] = eos_mask (unused by reference)
    const float* prior   = (const float*)d_in[2];
    const int*   adj     = (const int*)d_in[3];
    const float* Wk      = (const float*)d_in[4];
    const float* bk      = (const float*)d_in[5];
    const float* Wq      = (const float*)d_in[6];
    const float* bq      = (const float*)d_in[7];
    const float* gamma   = (const float*)d_in[8];
    const float* beta    = (const float*)d_in[9];

    float* out   = (float*)d_out;
    float* gout  = out;          // first output: g_attn (scores scratch first)
    float* naout = out + BSS;    // second output: neibor_attn (attn in-place)

    // workspace layout (~39 MB)
    char* ws = (char*)d_ws;
    short*  xb   = (short*)(ws);                        // 16 MB  x (bf16)
    short*  wqt  = (short*)(ws + (16ull << 20));        //  2 MB  Wq^T (bf16)
    short*  wkt  = (short*)(ws + (18ull << 20));        //  2 MB  Wk^T (bf16)
    short*  m2t  = (short*)(ws + (20ull << 20));        //  2 MB  (Wq^T Wk)^T
    short*  tb   = (short*)(ws + (22ull << 20));        // 16 MB  t = x@M2
    double* cumd = (double*)(ws + (38ull << 20));       // 64 KB
    float*  uvec = (float*)(ws + (38ull << 20) + (1ull << 16)); // 4 KB
    float*  vvec = uvec + 1024;                         // 4 KB
    float*  c0   = vvec + 1024;                         // 4 B (padded)
    float*  pvec = c0 + 64;                             // 32 KB (8192 f32)
    float*  rvec = pvec + 8192;                         // 32 KB
    float*  pu   = rvec + 8192;                         // 64 KB (16x1024)
    float*  pv   = pu + 16384;                          // 64 KB

    bias_gemv1<<<dim3(8, 16), 256, 0, stream>>>(Wq, Wk, bk, bq, pu, pv);
    bias_gemv2<<<4, 256, 0, stream>>>(pu, pv, bk, bq, uvec, vvec, c0);
    ln_kernel<<<8192, 256, 0, stream>>>(context, gamma, beta, uvec, vvec,
                                        xb, pvec, rvec);
    cvt_t_kernel<<<dim3(32, 32, 2), 256, 0, stream>>>(Wq, Wk, wqt, wkt);
    // M2T[j][i] = sum_d Wkt[j][d] * Wqt[i][d]  ( = (Wq^T Wk)[i][j] )
    gemm_bf16<<<dim3(8, 8), 256, 0, stream>>>(wkt, wqt, m2t);
    // t[q][j] = sum_i xb[q][i] * M2T[j][i]
    gemm_bf16<<<dim3(64, 8), 256, 0, stream>>>(xb, m2t, tb);
    // scores[b][q][k] = (t[q].x[k] + p[q] + r[k] + c0) / 512
    gemm_scores<<<dim3(8, 8, 8), 256, 0, stream>>>(tb, xb, pvec, rvec, c0, gout);
    softmax_kernel<<<8192, 256, 0, stream>>>(gout, adj, naout);
    cum2_kernel<<<8, 1024, 0, stream>>>(naout, prior, cumd);
    na_g_kernel<<<dim3(1024, 8), 256, 0, stream>>>(naout, prior, cumd, gout);
}

// Round 7
// 141.223 us; speedup vs baseline: 1.2201x; 1.0360x over previous
//
#include <hip/hip_runtime.h>
#include <hip/hip_bf16.h>

// Shapes (fixed for this problem)
#define S_LEN 1024
#define D_DIM 1024
#define N_BAT 8
#define BSS   (8ull*1024ull*1024ull)   // B*S*S elements per output

using bf16x8 = __attribute__((ext_vector_type(8))) short;
using f32x4  = __attribute__((ext_vector_type(4))) float;

__device__ __forceinline__ short f2bf(float v) {
    __hip_bfloat16 h = __float2bfloat16(v);
    return *reinterpret_cast<short*>(&h);
}

__device__ __forceinline__ void gload_lds16(const void* g, void* l) {
    __builtin_amdgcn_global_load_lds(
        (const __attribute__((address_space(1))) void*)g,
        (__attribute__((address_space(3))) void*)l, 16, 0, 0);
}

// XCD-aware bijective block remap (requires nwg % 8 == 0).
__device__ __forceinline__ int xcd_remap_flat() {
    const int nwg  = gridDim.x * gridDim.y * gridDim.z;
    const int flat = blockIdx.x + gridDim.x * (blockIdx.y + gridDim.y * blockIdx.z);
    const int cpx  = nwg >> 3;
    return (flat & 7) * cpx + (flat >> 3);
}

// ---------------------------------------------------------------------------
// 8-wave GEMM mainloop: 128x128 tile, BK=64, double-buffered LDS, 512 thr.
// Each wave owns a 64x32 output sub-tile: wr=w>>2 (0..1), wc=w&3 (0..3),
// acc[4][2] of 16x16 frags. Staging: 4 gload_lds16/thread/K-tile.
// T2 XOR swizzle (rule #21): LDS dest linear, global SOURCE pre-swizzled
// byte^((row&7)<<4), same XOR on ds_read. STAGE(next) before compute(cur),
// one barrier per K-tile.
// ---------------------------------------------------------------------------
__device__ __forceinline__ void gemm_mainloop8(
    const short* __restrict__ A, const short* __restrict__ Bt,
    int brow, int bcol, int kstart, int kIters,
    short* As, short* Bs, f32x4 acc[4][2])
{
    const int tid  = threadIdx.x;
    const int lane = tid & 63;
    const int w    = tid >> 6;
    const int wr   = w >> 2;            // 0..1
    const int wc   = w & 3;             // 0..3
    const int rsel = lane & 15;
    const int kb   = (lane >> 4) * 16;  // byte offset of 16B k-chunk

    // staging geometry (16KB buffer = 128 rows x 128 B)
    const int b0   = w * 1024;          // wave-uniform LDS base, chunk 0
    const int b1   = 8192 + w * 1024;   // chunk 1
    const int ch0  = b0 + lane * 16;
    const int ch1  = b1 + lane * 16;
    const int row0 = ch0 >> 7;
    const int cb0  = (ch0 & 127) ^ ((row0 & 7) << 4);
    const int row1 = ch1 >> 7;
    const int cb1  = (ch1 & 127) ^ ((row1 & 7) << 4);

#pragma unroll
    for (int m = 0; m < 4; ++m)
#pragma unroll
        for (int n = 0; n < 2; ++n) acc[m][n] = 0.0f;

    // prologue: stage K-tile kstart into buffer 0
    {
        char* Ad = (char*)As;
        char* Bd = (char*)Bs;
        gload_lds16((const char*)(A  + (size_t)(brow + row0) * 1024 + kstart) + cb0, Ad + b0);
        gload_lds16((const char*)(A  + (size_t)(brow + row1) * 1024 + kstart) + cb1, Ad + b1);
        gload_lds16((const char*)(Bt + (size_t)(bcol + row0) * 1024 + kstart) + cb0, Bd + b0);
        gload_lds16((const char*)(Bt + (size_t)(bcol + row1) * 1024 + kstart) + cb1, Bd + b1);
    }
    __syncthreads();

    for (int t = 0; t < kIters; ++t) {
        const int cur = t & 1;
        const char* Ac = (const char*)As + cur * 16384;
        const char* Bc = (const char*)Bs + cur * 16384;
        if (t + 1 < kIters) {            // issue next-tile loads FIRST
            const int k0 = kstart + (t + 1) * 64;
            char* An = (char*)As + (cur ^ 1) * 16384;
            char* Bn = (char*)Bs + (cur ^ 1) * 16384;
            gload_lds16((const char*)(A  + (size_t)(brow + row0) * 1024 + k0) + cb0, An + b0);
            gload_lds16((const char*)(A  + (size_t)(brow + row1) * 1024 + k0) + cb1, An + b1);
            gload_lds16((const char*)(Bt + (size_t)(bcol + row0) * 1024 + k0) + cb0, Bn + b0);
            gload_lds16((const char*)(Bt + (size_t)(bcol + row1) * 1024 + k0) + cb1, Bn + b1);
        }
        bf16x8 af[4][2], bfr[2][2];
#pragma unroll
        for (int m = 0; m < 4; ++m) {
            const int row = wr * 64 + m * 16 + rsel;
            const int sw  = (row & 7) << 4;
#pragma unroll
            for (int kk = 0; kk < 2; ++kk)
                af[m][kk] = *(const bf16x8*)&Ac[row * 128 + ((kk * 64 + kb) ^ sw)];
        }
#pragma unroll
        for (int n = 0; n < 2; ++n) {
            const int row = wc * 32 + n * 16 + rsel;
            const int sw  = (row & 7) << 4;
#pragma unroll
            for (int kk = 0; kk < 2; ++kk)
                bfr[n][kk] = *(const bf16x8*)&Bc[row * 128 + ((kk * 64 + kb) ^ sw)];
        }
#pragma unroll
        for (int kk = 0; kk < 2; ++kk)
#pragma unroll
            for (int m = 0; m < 4; ++m)
#pragma unroll
                for (int n = 0; n < 2; ++n)
                    acc[m][n] = __builtin_amdgcn_mfma_f32_16x16x32_bf16(
                        af[m][kk], bfr[n][kk], acc[m][n], 0, 0, 0);
        __syncthreads();   // drains next-tile loads + releases buffers
    }
}

// ---------------------------------------------------------------------------
// 3a) bf16-out GEMM for t = xb @ m2t^T. Grid MUST be (64, 8).
//     XCD mapping: each XCD gets 8 row-tiles x all 8 col-tiles
//     (A-panel 2MB + full B 2MB = 4MB, fits XCD L2).
// ---------------------------------------------------------------------------
__global__ __launch_bounds__(512) void gemm_bf16(
    const short* __restrict__ A, const short* __restrict__ Bt,
    short* __restrict__ C)
{
    __shared__ short As[2 * 8192];
    __shared__ short Bs[2 * 8192];
    const int nid = xcd_remap_flat();          // nid = xcd*64 + t
    const int mx  = ((nid >> 6) << 3) + (nid & 7);
    const int ny  = (nid >> 3) & 7;
    const int brow = mx * 128, bcol = ny * 128;

    f32x4 acc[4][2];
    gemm_mainloop8(A, Bt, brow, bcol, 0, 16, As, Bs, acc);

    const int lane = threadIdx.x & 63;
    const int w    = threadIdx.x >> 6;
    const int wr   = w >> 2, wc = w & 3;
#pragma unroll
    for (int m = 0; m < 4; ++m)
#pragma unroll
        for (int n = 0; n < 2; ++n) {
            const int colg = bcol + wc * 32 + n * 16 + (lane & 15);
#pragma unroll
            for (int r = 0; r < 4; ++r) {
                const int rowg = brow + wr * 64 + m * 16 + ((lane >> 4) * 4 + r);
                C[(size_t)rowg * 1024 + colg] = f2bf(acc[m][n][r]);
            }
        }
}

// ---------------------------------------------------------------------------
// 3b) Scores GEMM (batched): Sc[b][q][k] = (t[q].x[k] + p[q] + r[k] + c0)/512
//     Grid (8,8,8); XCD mapping: one batch per XCD (t+x slices = 4MB in L2).
// ---------------------------------------------------------------------------
__global__ __launch_bounds__(512) void gemm_scores(
    const short* __restrict__ Tm, const short* __restrict__ Xm,
    const float* __restrict__ p, const float* __restrict__ r2,
    const float* __restrict__ c0p, float* __restrict__ Sc)
{
    __shared__ short As[2 * 8192];
    __shared__ short Bs[2 * 8192];
    const int nid = xcd_remap_flat();
    const int mx  = nid & 7;
    const int ny  = (nid >> 3) & 7;
    const int b   = nid >> 6;               // one batch per XCD
    const short* A  = Tm + (size_t)b * 1024 * 1024;
    const short* Bt = Xm + (size_t)b * 1024 * 1024;
    const float* pb = p  + (size_t)b * 1024;
    const float* rb = r2 + (size_t)b * 1024;
    float* C = Sc + (size_t)b * 1024 * 1024;
    const int brow = mx * 128, bcol = ny * 128;

    f32x4 acc[4][2];
    gemm_mainloop8(A, Bt, brow, bcol, 0, 16, As, Bs, acc);

    const int lane = threadIdx.x & 63;
    const int w    = threadIdx.x >> 6;
    const int wr   = w >> 2, wc = w & 3;
    const float c0v = c0p[0];
#pragma unroll
    for (int m = 0; m < 4; ++m)
#pragma unroll
        for (int n = 0; n < 2; ++n) {
            const int colg = bcol + wc * 32 + n * 16 + (lane & 15);
            const float radd = rb[colg] + c0v;
#pragma unroll
            for (int r = 0; r < 4; ++r) {
                const int rowg = brow + wr * 64 + m * 16 + ((lane >> 4) * 4 + r);
                C[(size_t)rowg * 1024 + colg] =
                    (acc[m][n][r] + pb[rowg] + radd) * 0.001953125f; // /512
            }
        }
}

// ---------------------------------------------------------------------------
// 3c) M2T split-K GEMM: partial[z][j][i] = sum_{d in z-th 256} Wkt[j][d]Wqt[i][d]
//     Grid (8,8,4), f32 partials (no remap — tiny kernel).
// ---------------------------------------------------------------------------
__global__ __launch_bounds__(512) void gemm_splitk(
    const short* __restrict__ A, const short* __restrict__ Bt,
    float* __restrict__ P)
{
    __shared__ short As[2 * 8192];
    __shared__ short Bs[2 * 8192];
    const int brow = blockIdx.x * 128, bcol = blockIdx.y * 128;
    const int z = blockIdx.z;

    f32x4 acc[4][2];
    gemm_mainloop8(A, Bt, brow, bcol, z * 256, 4, As, Bs, acc);

    float* Pz = P + (size_t)z * 1024 * 1024;
    const int lane = threadIdx.x & 63;
    const int w    = threadIdx.x >> 6;
    const int wr   = w >> 2, wc = w & 3;
#pragma unroll
    for (int m = 0; m < 4; ++m)
#pragma unroll
        for (int n = 0; n < 2; ++n) {
            const int colg = bcol + wc * 32 + n * 16 + (lane & 15);
#pragma unroll
            for (int r = 0; r < 4; ++r) {
                const int rowg = brow + wr * 64 + m * 16 + ((lane >> 4) * 4 + r);
                Pz[(size_t)rowg * 1024 + colg] = acc[m][n][r];
            }
        }
}

// ---------------------------------------------------------------------------
// 3d) Reduce split-K partials -> bf16 m2t
// ---------------------------------------------------------------------------
__global__ __launch_bounds__(256) void reduce_m2t(
    const float* __restrict__ P, short* __restrict__ M)
{
    const int idx = blockIdx.x * 256 + threadIdx.x;   // 0..262143 (float4 units)
    const float4* P4 = (const float4*)P;
    float4 s = P4[idx];
    const float4 s1 = P4[idx + 262144];
    const float4 s2 = P4[idx + 524288];
    const float4 s3 = P4[idx + 786432];
    s.x += s1.x + s2.x + s3.x;
    s.y += s1.y + s2.y + s3.y;
    s.z += s1.z + s2.z + s3.z;
    s.w += s1.w + s2.w + s3.w;
    short4 o;
    o.x = f2bf(s.x); o.y = f2bf(s.y); o.z = f2bf(s.z); o.w = f2bf(s.w);
    ((short4*)M)[idx] = o;
}

// ---------------------------------------------------------------------------
// 0a) Bias GEMV stage 1: partial sums of u = Wq^T bk, v = Wk^T bq.
// ---------------------------------------------------------------------------
__global__ __launch_bounds__(256) void bias_gemv1(
    const float* __restrict__ Wq, const float* __restrict__ Wk,
    const float* __restrict__ bk, const float* __restrict__ bq,
    float* __restrict__ pu, float* __restrict__ pv)
{
    __shared__ float su[8][128];
    __shared__ float sv[8][128];
    const int tx = threadIdx.x & 31;
    const int ty = threadIdx.x >> 5;
    const int colBase = blockIdx.x * 128;
    const int rowBase = blockIdx.y * 64;
    const int i = colBase + tx * 4;
    float4 au = {0,0,0,0}, av = {0,0,0,0};
#pragma unroll
    for (int jj = 0; jj < 8; ++jj) {
        const int j = rowBase + ty + jj * 8;
        const float bkv = bk[j], bqv = bq[j];
        const float4 wq = *(const float4*)&Wq[(size_t)j * 1024 + i];
        const float4 wk = *(const float4*)&Wk[(size_t)j * 1024 + i];
        au.x += wq.x * bkv; au.y += wq.y * bkv; au.z += wq.z * bkv; au.w += wq.w * bkv;
        av.x += wk.x * bqv; av.y += wk.y * bqv; av.z += wk.z * bqv; av.w += wk.w * bqv;
    }
    ((float4*)su[ty])[tx] = au;
    ((float4*)sv[ty])[tx] = av;
    __syncthreads();
    if (ty == 0) {
        float4 s1 = ((float4*)su[0])[tx];
        float4 s2 = ((float4*)sv[0])[tx];
#pragma unroll
        for (int k = 1; k < 8; ++k) {
            const float4 t1 = ((float4*)su[k])[tx];
            const float4 t2 = ((float4*)sv[k])[tx];
            s1.x += t1.x; s1.y += t1.y; s1.z += t1.z; s1.w += t1.w;
            s2.x += t2.x; s2.y += t2.y; s2.z += t2.z; s2.w += t2.w;
        }
        ((float4*)&pu[(size_t)blockIdx.y * 1024 + colBase])[tx] = s1;
        ((float4*)&pv[(size_t)blockIdx.y * 1024 + colBase])[tx] = s2;
    }
}

// ---------------------------------------------------------------------------
// 0b) Bias GEMV stage 2: reduce 16 partials per column; also c0 = bq.bk
// ---------------------------------------------------------------------------
__global__ __launch_bounds__(256) void bias_gemv2(
    const float* __restrict__ pu, const float* __restrict__ pv,
    const float* __restrict__ bk, const float* __restrict__ bq,
    float* __restrict__ u, float* __restrict__ v, float* __restrict__ c0)
{
    __shared__ float sh[4];
    const int i = blockIdx.x * 256 + threadIdx.x;
    float su = 0.0f, sv = 0.0f;
#pragma unroll
    for (int k = 0; k < 16; ++k) {
        su += pu[k * 1024 + i];
        sv += pv[k * 1024 + i];
    }
    u[i] = su;
    v[i] = sv;
    if (blockIdx.x == 0) {
        const int t = threadIdx.x;
        const float4 a = ((const float4*)bq)[t];
        const float4 b = ((const float4*)bk)[t];
        float s = a.x*b.x + a.y*b.y + a.z*b.z + a.w*b.w;
        for (int off = 32; off > 0; off >>= 1) s += __shfl_down(s, off);
        const int lane = t & 63, w = t >> 6;
        if (lane == 0) sh[w] = s;
        __syncthreads();
        if (t == 0) c0[0] = sh[0] + sh[1] + sh[2] + sh[3];
    }
}

// ---------------------------------------------------------------------------
// 1) LayerNorm -> bf16; also emits p[row] = y.u and r2[row] = y.v
// ---------------------------------------------------------------------------
__global__ __launch_bounds__(256) void ln_kernel(
    const float* __restrict__ X, const float* __restrict__ gamma,
    const float* __restrict__ beta, const float* __restrict__ u,
    const float* __restrict__ v2, short* __restrict__ Y,
    float* __restrict__ p, float* __restrict__ r2)
{
    __shared__ float sh[16];
    const size_t row = blockIdx.x;
    const int t = threadIdx.x;
    float4 v = ((const float4*)(X + row * 1024))[t];
    float s  = v.x + v.y + v.z + v.w;
    float ss = v.x*v.x + v.y*v.y + v.z*v.z + v.w*v.w;
    for (int off = 32; off > 0; off >>= 1) {
        s  += __shfl_down(s, off);
        ss += __shfl_down(ss, off);
    }
    const int lane = t & 63, w = t >> 6;
    if (lane == 0) { sh[w] = s; sh[4 + w] = ss; }
    __syncthreads();
    if (t == 0) {
        float S  = sh[0] + sh[1] + sh[2] + sh[3];
        float SS = sh[4] + sh[5] + sh[6] + sh[7];
        float mu = S * (1.0f / 1024.0f);
        float var = fmaxf((SS - S * mu) * (1.0f / 1023.0f), 0.0f);
        sh[0] = mu;
        sh[1] = 1.0f / (sqrtf(var) + 1e-6f);
    }
    __syncthreads();
    const float mu = sh[0], inv = sh[1];
    float4 g  = ((const float4*)gamma)[t];
    float4 be = ((const float4*)beta)[t];
    float y0 = g.x * (v.x - mu) * inv + be.x;
    float y1 = g.y * (v.y - mu) * inv + be.y;
    float y2 = g.z * (v.z - mu) * inv + be.z;
    float y3 = g.w * (v.w - mu) * inv + be.w;
    short4 o;
    o.x = f2bf(y0); o.y = f2bf(y1); o.z = f2bf(y2); o.w = f2bf(y3);
    ((short4*)(Y + row * 1024))[t] = o;
    float4 uu = ((const float4*)u)[t];
    float4 vv = ((const float4*)v2)[t];
    float dp = y0*uu.x + y1*uu.y + y2*uu.z + y3*uu.w;
    float dr = y0*vv.x + y1*vv.y + y2*vv.z + y3*vv.w;
    for (int off = 32; off > 0; off >>= 1) {
        dp += __shfl_down(dp, off);
        dr += __shfl_down(dr, off);
    }
    if (lane == 0) { sh[8 + w] = dp; sh[12 + w] = dr; }
    __syncthreads();
    if (t == 0) {
        p[row]  = sh[8] + sh[9] + sh[10] + sh[11];
        r2[row] = sh[12] + sh[13] + sh[14] + sh[15];
    }
}

// ---------------------------------------------------------------------------
// 2) Transpose + convert Wq, Wk (f32 [D][D]) -> bf16 transposed copies
// ---------------------------------------------------------------------------
__global__ __launch_bounds__(256) void cvt_t_kernel(
    const float* __restrict__ Wq, const float* __restrict__ Wk,
    short* __restrict__ wqt, short* __restrict__ wkt)
{
    __shared__ float T[32][33];
    const float* src = blockIdx.z ? Wk : Wq;
    short* dst = blockIdx.z ? wkt : wqt;
    const int bi = blockIdx.x * 32, bj = blockIdx.y * 32;
    const int c = threadIdx.x & 31, r0 = threadIdx.x >> 5;
#pragma unroll
    for (int rr = 0; rr < 4; ++rr) {
        const int r = r0 + rr * 8;
        T[r][c] = src[(size_t)(bi + r) * 1024 + bj + c];
    }
    __syncthreads();
#pragma unroll
    for (int rr = 0; rr < 4; ++rr) {
        const int r = r0 + rr * 8;
        dst[(size_t)(bj + r) * 1024 + bi + c] = f2bf(T[c][r]);
    }
}

// ---------------------------------------------------------------------------
// 5) Masked row softmax: block per (b,q) row
// ---------------------------------------------------------------------------
__global__ __launch_bounds__(256) void softmax_kernel(
    const float* __restrict__ Sc, const int* __restrict__ adj,
    float* __restrict__ At)
{
    __shared__ float sh[4];
    const size_t row = blockIdx.x;
    const int t = threadIdx.x;
    const float4 sv = ((const float4*)(Sc + row * 1024))[t];
    const int4   av = ((const int4*)(adj + row * 1024))[t];
    float m = -3.0e38f;
    if (av.x) m = fmaxf(m, sv.x);
    if (av.y) m = fmaxf(m, sv.y);
    if (av.z) m = fmaxf(m, sv.z);
    if (av.w) m = fmaxf(m, sv.w);
    for (int off = 32; off > 0; off >>= 1) m = fmaxf(m, __shfl_down(m, off));
    const int lane = t & 63, w = t >> 6;
    if (lane == 0) sh[w] = m;
    __syncthreads();
    const float M = fmaxf(fmaxf(sh[0], sh[1]), fmaxf(sh[2], sh[3]));
    __syncthreads();
    float e0 = av.x ? expf(sv.x - M) : 0.0f;
    float e1 = av.y ? expf(sv.y - M) : 0.0f;
    float e2 = av.z ? expf(sv.z - M) : 0.0f;
    float e3 = av.w ? expf(sv.w - M) : 0.0f;
    float s = e0 + e1 + e2 + e3;
    for (int off = 32; off > 0; off >>= 1) s += __shfl_down(s, off);
    if (lane == 0) sh[w] = s;
    __syncthreads();
    const float Sm = sh[0] + sh[1] + sh[2] + sh[3];
    float4 o;
    if (Sm > 0.0f) {
        const float inv = 1.0f / Sm;
        o.x = e0 * inv; o.y = e1 * inv; o.z = e2 * inv; o.w = e3 * inv;
    } else {
        o.x = o.y = o.z = o.w = 1.0f / 1024.0f;
    }
    ((float4*)(At + row * 1024))[t] = o;
}

// ---------------------------------------------------------------------------
// 6) Prefix sums of L[k]=log(na[k,k+1]+1e-9) per batch (f64 scan in LDS)
// ---------------------------------------------------------------------------
__global__ __launch_bounds__(1024) void cum2_kernel(
    const float* __restrict__ At, const float* __restrict__ prior_p,
    double* __restrict__ cum)
{
    __shared__ double sh[1024];
    const int b = blockIdx.x;
    const int t = threadIdx.x;
    const float prior = *prior_p;
    const float om = 1.0f - prior;
    const float* attn = At + (size_t)b * 1024 * 1024;
    double v = 0.0;
    if (t >= 1) {
        const int k = t - 1;
        const float a1 = attn[(size_t)k * 1024 + (k + 1)];
        const float a2 = attn[(size_t)(k + 1) * 1024 + k];
        const float na = prior + om * sqrtf(a1 * a2 + 1e-9f);
        v = (double)logf(na + 1e-9f);
    }
    sh[t] = v;
    __syncthreads();
#pragma unroll
    for (int off = 1; off < 1024; off <<= 1) {
        const double add = (t >= off) ? sh[t - off] : 0.0;
        __syncthreads();
        sh[t] += add;
        __syncthreads();
    }
    cum[b * 1024 + t] = sh[t];
}

// ---------------------------------------------------------------------------
// 7) Fused na (in place) + g_attn fill. 32x32 tile-pair per block.
// ---------------------------------------------------------------------------
__global__ __launch_bounds__(256) void na_g_kernel(
    float* __restrict__ At, const float* __restrict__ prior_p,
    const double* __restrict__ cum, float* __restrict__ G)
{
    const int ti = blockIdx.x >> 5, tj = blockIdx.x & 31;
    if (tj < ti) return;
    const int b = blockIdx.y;
    const float prior = *prior_p;
    const float om = 1.0f - prior;
    float* base = At + (size_t)b * 1024 * 1024;
    float* gb   = G  + (size_t)b * 1024 * 1024;
    const double* cb = cum + (size_t)b * 1024;
    __shared__ float T1[32][33];
    __shared__ float T2[32][33];
    const int c = threadIdx.x & 31, r0 = threadIdx.x >> 5;
#pragma unroll
    for (int rr = 0; rr < 4; ++rr) {
        const int r = r0 + rr * 8;
        T1[r][c] = base[(size_t)(ti * 32 + r) * 1024 + tj * 32 + c];
        T2[r][c] = base[(size_t)(tj * 32 + r) * 1024 + ti * 32 + c];
    }
    __syncthreads();
#pragma unroll
    for (int rr = 0; rr < 4; ++rr) {
        const int r = r0 + rr * 8;
        const int R1 = ti * 32 + r, C1 = tj * 32 + c;
        const float na1 = prior + om * sqrtf(T1[r][c] * T2[c][r] + 1e-9f);
        base[(size_t)R1 * 1024 + C1] = na1;
        float g1;
        if (R1 == C1) g1 = na1;
        else {
            const int lo = min(R1, C1), hi = max(R1, C1);
            g1 = expf((float)(cb[hi] - cb[lo])) + 1e-9f;
        }
        gb[(size_t)R1 * 1024 + C1] = g1;
        const int R2 = tj * 32 + r, C2 = ti * 32 + c;
        const float na2 = prior + om * sqrtf(T2[r][c] * T1[c][r] + 1e-9f);
        base[(size_t)R2 * 1024 + C2] = na2;
        float g2;
        if (R2 == C2) g2 = na2;
        else {
            const int lo = min(R2, C2), hi = max(R2, C2);
            g2 = expf((float)(cb[hi] - cb[lo])) + 1e-9f;
        }
        gb[(size_t)R2 * 1024 + C2] = g2;
    }
}

// ---------------------------------------------------------------------------
extern "C" void kernel_launch(void* const* d_in, const int* in_sizes, int n_in,
                              void* d_out, int out_size, void* d_ws, size_t ws_size,
                              hipStream_t stream)
{
    const float* context = (const float*)d_in[0];
    // d_in[1] = eos_mask (unused by reference)
    const float* prior   = (const float*)d_in[2];
    const int*   adj     = (const int*)d_in[3];
    const float* Wk      = (const float*)d_in[4];
    const float* bk      = (const float*)d_in[5];
    const float* Wq      = (const float*)d_in[6];
    const float* bq      = (const float*)d_in[7];
    const float* gamma   = (const float*)d_in[8];
    const float* beta    = (const float*)d_in[9];

    float* out   = (float*)d_out;
    float* gout  = out;          // first output: g_attn (scores scratch first)
    float* naout = out + BSS;    // second output: neibor_attn (attn in-place)

    // workspace layout (~39 MB)
    char* ws = (char*)d_ws;
    short*  xb    = (short*)(ws);                        // 16 MB  x (bf16)
    short*  wqt   = (short*)(ws + (16ull << 20));        //  2 MB  Wq^T (bf16)
    short*  wkt   = (short*)(ws + (18ull << 20));        //  2 MB  Wk^T (bf16)
    short*  m2t   = (short*)(ws + (20ull << 20));        //  2 MB  (Wq^T Wk)^T
    short*  tb    = (short*)(ws + (22ull << 20));        // 16 MB  t = x@M2
    float*  m2par = (float*)tb;                          // 16 MB  split-K partials (aliased; consumed before tb written)
    double* cumd  = (double*)(ws + (38ull << 20));       // 64 KB
    float*  uvec  = (float*)(ws + (38ull << 20) + (1ull << 16)); // 4 KB
    float*  vvec  = uvec + 1024;                         // 4 KB
    float*  c0    = vvec + 1024;                         // 4 B (padded)
    float*  pvec  = c0 + 64;                             // 32 KB (8192 f32)
    float*  rvec  = pvec + 8192;                         // 32 KB
    float*  pu    = rvec + 8192;                         // 64 KB (16x1024)
    float*  pv    = pu + 16384;                          // 64 KB

    bias_gemv1<<<dim3(8, 16), 256, 0, stream>>>(Wq, Wk, bk, bq, pu, pv);
    bias_gemv2<<<4, 256, 0, stream>>>(pu, pv, bk, bq, uvec, vvec, c0);
    ln_kernel<<<8192, 256, 0, stream>>>(context, gamma, beta, uvec, vvec,
                                        xb, pvec, rvec);
    cvt_t_kernel<<<dim3(32, 32, 2), 256, 0, stream>>>(Wq, Wk, wqt, wkt);
    // M2T[j][i] = sum_d Wkt[j][d] * Wqt[i][d], split-K x4 + reduce
    gemm_splitk<<<dim3(8, 8, 4), 512, 0, stream>>>(wkt, wqt, m2par);
    reduce_m2t<<<1024, 256, 0, stream>>>(m2par, m2t);
    // t[q][j] = sum_i xb[q][i] * m2t[j][i]   (overwrites the partials slot)
    gemm_bf16<<<dim3(64, 8), 512, 0, stream>>>(xb, m2t, tb);
    // scores[b][q][k] = (t[q].x[k] + p[q] + r[k] + c0) / 512
    gemm_scores<<<dim3(8, 8, 8), 512, 0, stream>>>(tb, xb, pvec, rvec, c0, gout);
    softmax_kernel<<<8192, 256, 0, stream>>>(gout, adj, naout);
    cum2_kernel<<<8, 1024, 0, stream>>>(naout, prior, cumd);
    na_g_kernel<<<dim3(1024, 8), 256, 0, stream>>>(naout, prior, cumd, gout);
}

// Round 8
// 137.859 us; speedup vs baseline: 1.2498x; 1.0244x over previous
//
#include <hip/hip_runtime.h>
#include <hip/hip_bf16.h>

// Shapes (fixed for this problem)
#define S_LEN 1024
#define D_DIM 1024
#define N_BAT 8
#define BSS   (8ull*1024ull*1024ull)   // B*S*S elements per output

using bf16x8 = __attribute__((ext_vector_type(8))) short;
using f32x4  = __attribute__((ext_vector_type(4))) float;

__device__ __forceinline__ short f2bf(float v) {
    __hip_bfloat16 h = __float2bfloat16(v);
    return *reinterpret_cast<short*>(&h);
}

__device__ __forceinline__ void gload_lds16(const void* g, void* l) {
    __builtin_amdgcn_global_load_lds(
        (const __attribute__((address_space(1))) void*)g,
        (__attribute__((address_space(3))) void*)l, 16, 0, 0);
}

// XCD-aware bijective block remap (requires nwg % 8 == 0).
__device__ __forceinline__ int xcd_remap_flat() {
    const int nwg  = gridDim.x * gridDim.y * gridDim.z;
    const int flat = blockIdx.x + gridDim.x * (blockIdx.y + gridDim.y * blockIdx.z);
    const int cpx  = nwg >> 3;
    return (flat & 7) * cpx + (flat >> 3);
}

// ---------------------------------------------------------------------------
// Counted-vmcnt pipelined GEMM mainloop (T3+T4): 128x128 tile, BK=64,
// 4-deep LDS ring (4 x 16KB per operand = 128KB), 8 waves (512 thr),
// each wave owns a 64x32 sub-tile (acc[4][2]).
// Per iter: vmcnt(8) -> s_barrier -> issue tile t+3 -> ds_read+MFMA.
// vmcnt NEVER drains to 0 in steady state; loads get ~3 iters of slack.
// Correctness: each wave waits its OWN tile-t loads (vmcnt in-order), then
// the barrier publishes all waves' writes; buf[(t+3)&3] was last read at
// iter t-1, and the barrier also proves all waves finished those reads.
// T2 XOR swizzle unchanged (pre-swizzled global source, same XOR on ds_read).
// ---------------------------------------------------------------------------
template<int KITERS>
__device__ __forceinline__ void gemm_mainloop_pipe(
    const short* __restrict__ A, const short* __restrict__ Bt,
    int brow, int bcol, int kstart,
    short* As, short* Bs, f32x4 acc[4][2])
{
    const int tid  = threadIdx.x;
    const int lane = tid & 63;
    const int w    = tid >> 6;
    const int wr   = w >> 2;            // 0..1
    const int wc   = w & 3;             // 0..3
    const int rsel = lane & 15;
    const int kb   = (lane >> 4) * 16;  // byte offset of 16B k-chunk

    // staging geometry (each 16KB buffer = 128 rows x 128 B)
    const int b0   = w * 1024;          // wave-uniform LDS base, chunk 0
    const int b1   = 8192 + w * 1024;   // chunk 1
    const int ch0  = b0 + lane * 16;
    const int ch1  = b1 + lane * 16;
    const int row0 = ch0 >> 7;
    const int cb0  = (ch0 & 127) ^ ((row0 & 7) << 4);
    const int row1 = ch1 >> 7;
    const int cb1  = (ch1 & 127) ^ ((row1 & 7) << 4);

#pragma unroll
    for (int m = 0; m < 4; ++m)
#pragma unroll
        for (int n = 0; n < 2; ++n) acc[m][n] = 0.0f;

    // prologue: stage tiles 0..2 into ring slots 0..2
    constexpr int NPRE = (KITERS < 3) ? KITERS : 3;
#pragma unroll
    for (int i = 0; i < NPRE; ++i) {
        const int k0 = kstart + i * 64;
        char* Ad = (char*)As + i * 16384;
        char* Bd = (char*)Bs + i * 16384;
        gload_lds16((const char*)(A  + (size_t)(brow + row0) * 1024 + k0) + cb0, Ad + b0);
        gload_lds16((const char*)(A  + (size_t)(brow + row1) * 1024 + k0) + cb1, Ad + b1);
        gload_lds16((const char*)(Bt + (size_t)(bcol + row0) * 1024 + k0) + cb0, Bd + b0);
        gload_lds16((const char*)(Bt + (size_t)(bcol + row1) * 1024 + k0) + cb1, Bd + b1);
    }

#pragma unroll
    for (int t = 0; t < KITERS; ++t) {
        // tiles in flight beyond t at this point: min(2, KITERS-1-t); 4 loads each
        const int ahead = KITERS - 1 - t;
        if (ahead >= 2)      asm volatile("s_waitcnt vmcnt(8)" ::: "memory");
        else if (ahead == 1) asm volatile("s_waitcnt vmcnt(4)" ::: "memory");
        else                 asm volatile("s_waitcnt vmcnt(0)" ::: "memory");
        __builtin_amdgcn_s_barrier();
        asm volatile("" ::: "memory");   // no LDS access hoisted above barrier

        if (t + 3 < KITERS) {            // refill the slot freed at iter t-1
            const int k0 = kstart + (t + 3) * 64;
            char* An = (char*)As + ((t + 3) & 3) * 16384;
            char* Bn = (char*)Bs + ((t + 3) & 3) * 16384;
            gload_lds16((const char*)(A  + (size_t)(brow + row0) * 1024 + k0) + cb0, An + b0);
            gload_lds16((const char*)(A  + (size_t)(brow + row1) * 1024 + k0) + cb1, An + b1);
            gload_lds16((const char*)(Bt + (size_t)(bcol + row0) * 1024 + k0) + cb0, Bn + b0);
            gload_lds16((const char*)(Bt + (size_t)(bcol + row1) * 1024 + k0) + cb1, Bn + b1);
        }

        const char* Ac = (const char*)As + (t & 3) * 16384;
        const char* Bc = (const char*)Bs + (t & 3) * 16384;
        bf16x8 af[4][2], bfr[2][2];
#pragma unroll
        for (int m = 0; m < 4; ++m) {
            const int row = wr * 64 + m * 16 + rsel;
            const int sw  = (row & 7) << 4;
#pragma unroll
            for (int kk = 0; kk < 2; ++kk)
                af[m][kk] = *(const bf16x8*)&Ac[row * 128 + ((kk * 64 + kb) ^ sw)];
        }
#pragma unroll
        for (int n = 0; n < 2; ++n) {
            const int row = wc * 32 + n * 16 + rsel;
            const int sw  = (row & 7) << 4;
#pragma unroll
            for (int kk = 0; kk < 2; ++kk)
                bfr[n][kk] = *(const bf16x8*)&Bc[row * 128 + ((kk * 64 + kb) ^ sw)];
        }
#pragma unroll
        for (int kk = 0; kk < 2; ++kk)
#pragma unroll
            for (int m = 0; m < 4; ++m)
#pragma unroll
                for (int n = 0; n < 2; ++n)
                    acc[m][n] = __builtin_amdgcn_mfma_f32_16x16x32_bf16(
                        af[m][kk], bfr[n][kk], acc[m][n], 0, 0, 0);
        // no end-of-iter barrier: next iter's vmcnt+barrier provides it
    }
}

// ---------------------------------------------------------------------------
// 3a) bf16-out GEMM for t = xb @ m2t^T. Grid MUST be (64, 8).
//     XCD mapping: each XCD gets 8 row-tiles x all 8 col-tiles.
// ---------------------------------------------------------------------------
__global__ __launch_bounds__(512) void gemm_bf16(
    const short* __restrict__ A, const short* __restrict__ Bt,
    short* __restrict__ C)
{
    __shared__ short As[4 * 8192];
    __shared__ short Bs[4 * 8192];
    const int nid = xcd_remap_flat();          // nid = xcd*64 + t
    const int mx  = ((nid >> 6) << 3) + (nid & 7);
    const int ny  = (nid >> 3) & 7;
    const int brow = mx * 128, bcol = ny * 128;

    f32x4 acc[4][2];
    gemm_mainloop_pipe<16>(A, Bt, brow, bcol, 0, As, Bs, acc);

    const int lane = threadIdx.x & 63;
    const int w    = threadIdx.x >> 6;
    const int wr   = w >> 2, wc = w & 3;
#pragma unroll
    for (int m = 0; m < 4; ++m)
#pragma unroll
        for (int n = 0; n < 2; ++n) {
            const int colg = bcol + wc * 32 + n * 16 + (lane & 15);
#pragma unroll
            for (int r = 0; r < 4; ++r) {
                const int rowg = brow + wr * 64 + m * 16 + ((lane >> 4) * 4 + r);
                C[(size_t)rowg * 1024 + colg] = f2bf(acc[m][n][r]);
            }
        }
}

// ---------------------------------------------------------------------------
// 3b) Scores GEMM (batched): Sc[b][q][k] = (t[q].x[k] + p[q] + r[k] + c0)/512
//     Grid (8,8,8); one batch per XCD.
// ---------------------------------------------------------------------------
__global__ __launch_bounds__(512) void gemm_scores(
    const short* __restrict__ Tm, const short* __restrict__ Xm,
    const float* __restrict__ p, const float* __restrict__ r2,
    const float* __restrict__ c0p, float* __restrict__ Sc)
{
    __shared__ short As[4 * 8192];
    __shared__ short Bs[4 * 8192];
    const int nid = xcd_remap_flat();
    const int mx  = nid & 7;
    const int ny  = (nid >> 3) & 7;
    const int b   = nid >> 6;               // one batch per XCD
    const short* A  = Tm + (size_t)b * 1024 * 1024;
    const short* Bt = Xm + (size_t)b * 1024 * 1024;
    const float* pb = p  + (size_t)b * 1024;
    const float* rb = r2 + (size_t)b * 1024;
    float* C = Sc + (size_t)b * 1024 * 1024;
    const int brow = mx * 128, bcol = ny * 128;

    f32x4 acc[4][2];
    gemm_mainloop_pipe<16>(A, Bt, brow, bcol, 0, As, Bs, acc);

    const int lane = threadIdx.x & 63;
    const int w    = threadIdx.x >> 6;
    const int wr   = w >> 2, wc = w & 3;
    const float c0v = c0p[0];
#pragma unroll
    for (int m = 0; m < 4; ++m)
#pragma unroll
        for (int n = 0; n < 2; ++n) {
            const int colg = bcol + wc * 32 + n * 16 + (lane & 15);
            const float radd = rb[colg] + c0v;
#pragma unroll
            for (int r = 0; r < 4; ++r) {
                const int rowg = brow + wr * 64 + m * 16 + ((lane >> 4) * 4 + r);
                C[(size_t)rowg * 1024 + colg] =
                    (acc[m][n][r] + pb[rowg] + radd) * 0.001953125f; // /512
            }
        }
}

// ---------------------------------------------------------------------------
// 3c) M2T split-K GEMM: partial[z][j][i] = sum_{d in z-th 256} Wkt[j][d]Wqt[i][d]
// ---------------------------------------------------------------------------
__global__ __launch_bounds__(512) void gemm_splitk(
    const short* __restrict__ A, const short* __restrict__ Bt,
    float* __restrict__ P)
{
    __shared__ short As[4 * 8192];
    __shared__ short Bs[4 * 8192];
    const int brow = blockIdx.x * 128, bcol = blockIdx.y * 128;
    const int z = blockIdx.z;

    f32x4 acc[4][2];
    gemm_mainloop_pipe<4>(A, Bt, brow, bcol, z * 256, As, Bs, acc);

    float* Pz = P + (size_t)z * 1024 * 1024;
    const int lane = threadIdx.x & 63;
    const int w    = threadIdx.x >> 6;
    const int wr   = w >> 2, wc = w & 3;
#pragma unroll
    for (int m = 0; m < 4; ++m)
#pragma unroll
        for (int n = 0; n < 2; ++n) {
            const int colg = bcol + wc * 32 + n * 16 + (lane & 15);
#pragma unroll
            for (int r = 0; r < 4; ++r) {
                const int rowg = brow + wr * 64 + m * 16 + ((lane >> 4) * 4 + r);
                Pz[(size_t)rowg * 1024 + colg] = acc[m][n][r];
            }
        }
}

// ---------------------------------------------------------------------------
// 3d) Reduce split-K partials -> bf16 m2t
// ---------------------------------------------------------------------------
__global__ __launch_bounds__(256) void reduce_m2t(
    const float* __restrict__ P, short* __restrict__ M)
{
    const int idx = blockIdx.x * 256 + threadIdx.x;   // float4 units
    const float4* P4 = (const float4*)P;
    float4 s = P4[idx];
    const float4 s1 = P4[idx + 262144];
    const float4 s2 = P4[idx + 524288];
    const float4 s3 = P4[idx + 786432];
    s.x += s1.x + s2.x + s3.x;
    s.y += s1.y + s2.y + s3.y;
    s.z += s1.z + s2.z + s3.z;
    s.w += s1.w + s2.w + s3.w;
    short4 o;
    o.x = f2bf(s.x); o.y = f2bf(s.y); o.z = f2bf(s.z); o.w = f2bf(s.w);
    ((short4*)M)[idx] = o;
}

// ---------------------------------------------------------------------------
// 0a) Bias GEMV stage 1: partial sums of u = Wq^T bk, v = Wk^T bq.
// ---------------------------------------------------------------------------
__global__ __launch_bounds__(256) void bias_gemv1(
    const float* __restrict__ Wq, const float* __restrict__ Wk,
    const float* __restrict__ bk, const float* __restrict__ bq,
    float* __restrict__ pu, float* __restrict__ pv)
{
    __shared__ float su[8][128];
    __shared__ float sv[8][128];
    const int tx = threadIdx.x & 31;
    const int ty = threadIdx.x >> 5;
    const int colBase = blockIdx.x * 128;
    const int rowBase = blockIdx.y * 64;
    const int i = colBase + tx * 4;
    float4 au = {0,0,0,0}, av = {0,0,0,0};
#pragma unroll
    for (int jj = 0; jj < 8; ++jj) {
        const int j = rowBase + ty + jj * 8;
        const float bkv = bk[j], bqv = bq[j];
        const float4 wq = *(const float4*)&Wq[(size_t)j * 1024 + i];
        const float4 wk = *(const float4*)&Wk[(size_t)j * 1024 + i];
        au.x += wq.x * bkv; au.y += wq.y * bkv; au.z += wq.z * bkv; au.w += wq.w * bkv;
        av.x += wk.x * bqv; av.y += wk.y * bqv; av.z += wk.z * bqv; av.w += wk.w * bqv;
    }
    ((float4*)su[ty])[tx] = au;
    ((float4*)sv[ty])[tx] = av;
    __syncthreads();
    if (ty == 0) {
        float4 s1 = ((float4*)su[0])[tx];
        float4 s2 = ((float4*)sv[0])[tx];
#pragma unroll
        for (int k = 1; k < 8; ++k) {
            const float4 t1 = ((float4*)su[k])[tx];
            const float4 t2 = ((float4*)sv[k])[tx];
            s1.x += t1.x; s1.y += t1.y; s1.z += t1.z; s1.w += t1.w;
            s2.x += t2.x; s2.y += t2.y; s2.z += t2.z; s2.w += t2.w;
        }
        ((float4*)&pu[(size_t)blockIdx.y * 1024 + colBase])[tx] = s1;
        ((float4*)&pv[(size_t)blockIdx.y * 1024 + colBase])[tx] = s2;
    }
}

// ---------------------------------------------------------------------------
// 0b) Bias GEMV stage 2: reduce 16 partials per column; also c0 = bq.bk
// ---------------------------------------------------------------------------
__global__ __launch_bounds__(256) void bias_gemv2(
    const float* __restrict__ pu, const float* __restrict__ pv,
    const float* __restrict__ bk, const float* __restrict__ bq,
    float* __restrict__ u, float* __restrict__ v, float* __restrict__ c0)
{
    __shared__ float sh[4];
    const int i = blockIdx.x * 256 + threadIdx.x;
    float su = 0.0f, sv = 0.0f;
#pragma unroll
    for (int k = 0; k < 16; ++k) {
        su += pu[k * 1024 + i];
        sv += pv[k * 1024 + i];
    }
    u[i] = su;
    v[i] = sv;
    if (blockIdx.x == 0) {
        const int t = threadIdx.x;
        const float4 a = ((const float4*)bq)[t];
        const float4 b = ((const float4*)bk)[t];
        float s = a.x*b.x + a.y*b.y + a.z*b.z + a.w*b.w;
        for (int off = 32; off > 0; off >>= 1) s += __shfl_down(s, off);
        const int lane = t & 63, w = t >> 6;
        if (lane == 0) sh[w] = s;
        __syncthreads();
        if (t == 0) c0[0] = sh[0] + sh[1] + sh[2] + sh[3];
    }
}

// ---------------------------------------------------------------------------
// 1) LayerNorm -> bf16; also emits p[row] = y.u and r2[row] = y.v
// ---------------------------------------------------------------------------
__global__ __launch_bounds__(256) void ln_kernel(
    const float* __restrict__ X, const float* __restrict__ gamma,
    const float* __restrict__ beta, const float* __restrict__ u,
    const float* __restrict__ v2, short* __restrict__ Y,
    float* __restrict__ p, float* __restrict__ r2)
{
    __shared__ float sh[16];
    const size_t row = blockIdx.x;
    const int t = threadIdx.x;
    float4 v = ((const float4*)(X + row * 1024))[t];
    float s  = v.x + v.y + v.z + v.w;
    float ss = v.x*v.x + v.y*v.y + v.z*v.z + v.w*v.w;
    for (int off = 32; off > 0; off >>= 1) {
        s  += __shfl_down(s, off);
        ss += __shfl_down(ss, off);
    }
    const int lane = t & 63, w = t >> 6;
    if (lane == 0) { sh[w] = s; sh[4 + w] = ss; }
    __syncthreads();
    if (t == 0) {
        float S  = sh[0] + sh[1] + sh[2] + sh[3];
        float SS = sh[4] + sh[5] + sh[6] + sh[7];
        float mu = S * (1.0f / 1024.0f);
        float var = fmaxf((SS - S * mu) * (1.0f / 1023.0f), 0.0f);
        sh[0] = mu;
        sh[1] = 1.0f / (sqrtf(var) + 1e-6f);
    }
    __syncthreads();
    const float mu = sh[0], inv = sh[1];
    float4 g  = ((const float4*)gamma)[t];
    float4 be = ((const float4*)beta)[t];
    float y0 = g.x * (v.x - mu) * inv + be.x;
    float y1 = g.y * (v.y - mu) * inv + be.y;
    float y2 = g.z * (v.z - mu) * inv + be.z;
    float y3 = g.w * (v.w - mu) * inv + be.w;
    short4 o;
    o.x = f2bf(y0); o.y = f2bf(y1); o.z = f2bf(y2); o.w = f2bf(y3);
    ((short4*)(Y + row * 1024))[t] = o;
    float4 uu = ((const float4*)u)[t];
    float4 vv = ((const float4*)v2)[t];
    float dp = y0*uu.x + y1*uu.y + y2*uu.z + y3*uu.w;
    float dr = y0*vv.x + y1*vv.y + y2*vv.z + y3*vv.w;
    for (int off = 32; off > 0; off >>= 1) {
        dp += __shfl_down(dp, off);
        dr += __shfl_down(dr, off);
    }
    if (lane == 0) { sh[8 + w] = dp; sh[12 + w] = dr; }
    __syncthreads();
    if (t == 0) {
        p[row]  = sh[8] + sh[9] + sh[10] + sh[11];
        r2[row] = sh[12] + sh[13] + sh[14] + sh[15];
    }
}

// ---------------------------------------------------------------------------
// 2) Transpose + convert Wq, Wk (f32 [D][D]) -> bf16 transposed copies
// ---------------------------------------------------------------------------
__global__ __launch_bounds__(256) void cvt_t_kernel(
    const float* __restrict__ Wq, const float* __restrict__ Wk,
    short* __restrict__ wqt, short* __restrict__ wkt)
{
    __shared__ float T[32][33];
    const float* src = blockIdx.z ? Wk : Wq;
    short* dst = blockIdx.z ? wkt : wqt;
    const int bi = blockIdx.x * 32, bj = blockIdx.y * 32;
    const int c = threadIdx.x & 31, r0 = threadIdx.x >> 5;
#pragma unroll
    for (int rr = 0; rr < 4; ++rr) {
        const int r = r0 + rr * 8;
        T[r][c] = src[(size_t)(bi + r) * 1024 + bj + c];
    }
    __syncthreads();
#pragma unroll
    for (int rr = 0; rr < 4; ++rr) {
        const int r = r0 + rr * 8;
        dst[(size_t)(bj + r) * 1024 + bi + c] = f2bf(T[c][r]);
    }
}

// ---------------------------------------------------------------------------
// 5) Masked row softmax: block per (b,q) row
// ---------------------------------------------------------------------------
__global__ __launch_bounds__(256) void softmax_kernel(
    const float* __restrict__ Sc, const int* __restrict__ adj,
    float* __restrict__ At)
{
    __shared__ float sh[4];
    const size_t row = blockIdx.x;
    const int t = threadIdx.x;
    const float4 sv = ((const float4*)(Sc + row * 1024))[t];
    const int4   av = ((const int4*)(adj + row * 1024))[t];
    float m = -3.0e38f;
    if (av.x) m = fmaxf(m, sv.x);
    if (av.y) m = fmaxf(m, sv.y);
    if (av.z) m = fmaxf(m, sv.z);
    if (av.w) m = fmaxf(m, sv.w);
    for (int off = 32; off > 0; off >>= 1) m = fmaxf(m, __shfl_down(m, off));
    const int lane = t & 63, w = t >> 6;
    if (lane == 0) sh[w] = m;
    __syncthreads();
    const float M = fmaxf(fmaxf(sh[0], sh[1]), fmaxf(sh[2], sh[3]));
    __syncthreads();
    float e0 = av.x ? expf(sv.x - M) : 0.0f;
    float e1 = av.y ? expf(sv.y - M) : 0.0f;
    float e2 = av.z ? expf(sv.z - M) : 0.0f;
    float e3 = av.w ? expf(sv.w - M) : 0.0f;
    float s = e0 + e1 + e2 + e3;
    for (int off = 32; off > 0; off >>= 1) s += __shfl_down(s, off);
    if (lane == 0) sh[w] = s;
    __syncthreads();
    const float Sm = sh[0] + sh[1] + sh[2] + sh[3];
    float4 o;
    if (Sm > 0.0f) {
        const float inv = 1.0f / Sm;
        o.x = e0 * inv; o.y = e1 * inv; o.z = e2 * inv; o.w = e3 * inv;
    } else {
        o.x = o.y = o.z = o.w = 1.0f / 1024.0f;
    }
    ((float4*)(At + row * 1024))[t] = o;
}

// ---------------------------------------------------------------------------
// 6) Prefix sums of L[k]=log(na[k,k+1]+1e-9) per batch (f64 scan in LDS)
// ---------------------------------------------------------------------------
__global__ __launch_bounds__(1024) void cum2_kernel(
    const float* __restrict__ At, const float* __restrict__ prior_p,
    double* __restrict__ cum)
{
    __shared__ double sh[1024];
    const int b = blockIdx.x;
    const int t = threadIdx.x;
    const float prior = *prior_p;
    const float om = 1.0f - prior;
    const float* attn = At + (size_t)b * 1024 * 1024;
    double v = 0.0;
    if (t >= 1) {
        const int k = t - 1;
        const float a1 = attn[(size_t)k * 1024 + (k + 1)];
        const float a2 = attn[(size_t)(k + 1) * 1024 + k];
        const float na = prior + om * sqrtf(a1 * a2 + 1e-9f);
        v = (double)logf(na + 1e-9f);
    }
    sh[t] = v;
    __syncthreads();
#pragma unroll
    for (int off = 1; off < 1024; off <<= 1) {
        const double add = (t >= off) ? sh[t - off] : 0.0;
        __syncthreads();
        sh[t] += add;
        __syncthreads();
    }
    cum[b * 1024 + t] = sh[t];
}

// ---------------------------------------------------------------------------
// 7) Fused na (in place) + g_attn fill. 32x32 tile-pair per block.
// ---------------------------------------------------------------------------
__global__ __launch_bounds__(256) void na_g_kernel(
    float* __restrict__ At, const float* __restrict__ prior_p,
    const double* __restrict__ cum, float* __restrict__ G)
{
    const int ti = blockIdx.x >> 5, tj = blockIdx.x & 31;
    if (tj < ti) return;
    const int b = blockIdx.y;
    const float prior = *prior_p;
    const float om = 1.0f - prior;
    float* base = At + (size_t)b * 1024 * 1024;
    float* gb   = G  + (size_t)b * 1024 * 1024;
    const double* cb = cum + (size_t)b * 1024;
    __shared__ float T1[32][33];
    __shared__ float T2[32][33];
    const int c = threadIdx.x & 31, r0 = threadIdx.x >> 5;
#pragma unroll
    for (int rr = 0; rr < 4; ++rr) {
        const int r = r0 + rr * 8;
        T1[r][c] = base[(size_t)(ti * 32 + r) * 1024 + tj * 32 + c];
        T2[r][c] = base[(size_t)(tj * 32 + r) * 1024 + ti * 32 + c];
    }
    __syncthreads();
#pragma unroll
    for (int rr = 0; rr < 4; ++rr) {
        const int r = r0 + rr * 8;
        const int R1 = ti * 32 + r, C1 = tj * 32 + c;
        const float na1 = prior + om * sqrtf(T1[r][c] * T2[c][r] + 1e-9f);
        base[(size_t)R1 * 1024 + C1] = na1;
        float g1;
        if (R1 == C1) g1 = na1;
        else {
            const int lo = min(R1, C1), hi = max(R1, C1);
            g1 = expf((float)(cb[hi] - cb[lo])) + 1e-9f;
        }
        gb[(size_t)R1 * 1024 + C1] = g1;
        const int R2 = tj * 32 + r, C2 = ti * 32 + c;
        const float na2 = prior + om * sqrtf(T2[r][c] * T1[c][r] + 1e-9f);
        base[(size_t)R2 * 1024 + C2] = na2;
        float g2;
        if (R2 == C2) g2 = na2;
        else {
            const int lo = min(R2, C2), hi = max(R2, C2);
            g2 = expf((float)(cb[hi] - cb[lo])) + 1e-9f;
        }
        gb[(size_t)R2 * 1024 + C2] = g2;
    }
}

// ---------------------------------------------------------------------------
extern "C" void kernel_launch(void* const* d_in, const int* in_sizes, int n_in,
                              void* d_out, int out_size, void* d_ws, size_t ws_size,
                              hipStream_t stream)
{
    const float* context = (const float*)d_in[0];
    // d_in[1] = eos_mask (unused by reference)
    const float* prior   = (const float*)d_in[2];
    const int*   adj     = (const int*)d_in[3];
    const float* Wk      = (const float*)d_in[4];
    const float* bk      = (const float*)d_in[5];
    const float* Wq      = (const float*)d_in[6];
    const float* bq      = (const float*)d_in[7];
    const float* gamma   = (const float*)d_in[8];
    const float* beta    = (const float*)d_in[9];

    float* out   = (float*)d_out;
    float* gout  = out;          // first output: g_attn (scores scratch first)
    float* naout = out + BSS;    // second output: neibor_attn (attn in-place)

    // workspace layout (~39 MB)
    char* ws = (char*)d_ws;
    short*  xb    = (short*)(ws);                        // 16 MB  x (bf16)
    short*  wqt   = (short*)(ws + (16ull << 20));        //  2 MB  Wq^T (bf16)
    short*  wkt   = (short*)(ws + (18ull << 20));        //  2 MB  Wk^T (bf16)
    short*  m2t   = (short*)(ws + (20ull << 20));        //  2 MB  (Wq^T Wk)^T
    short*  tb    = (short*)(ws + (22ull << 20));        // 16 MB  t = x@M2
    float*  m2par = (float*)tb;                          // 16 MB  split-K partials (aliased; consumed before tb written)
    double* cumd  = (double*)(ws + (38ull << 20));       // 64 KB
    float*  uvec  = (float*)(ws + (38ull << 20) + (1ull << 16)); // 4 KB
    float*  vvec  = uvec + 1024;                         // 4 KB
    float*  c0    = vvec + 1024;                         // 4 B (padded)
    float*  pvec  = c0 + 64;                             // 32 KB (8192 f32)
    float*  rvec  = pvec + 8192;                         // 32 KB
    float*  pu    = rvec + 8192;                         // 64 KB (16x1024)
    float*  pv    = pu + 16384;                          // 64 KB

    bias_gemv1<<<dim3(8, 16), 256, 0, stream>>>(Wq, Wk, bk, bq, pu, pv);
    bias_gemv2<<<4, 256, 0, stream>>>(pu, pv, bk, bq, uvec, vvec, c0);
    ln_kernel<<<8192, 256, 0, stream>>>(context, gamma, beta, uvec, vvec,
                                        xb, pvec, rvec);
    cvt_t_kernel<<<dim3(32, 32, 2), 256, 0, stream>>>(Wq, Wk, wqt, wkt);
    // M2T[j][i] = sum_d Wkt[j][d] * Wqt[i][d], split-K x4 + reduce
    gemm_splitk<<<dim3(8, 8, 4), 512, 0, stream>>>(wkt, wqt, m2par);
    reduce_m2t<<<1024, 256, 0, stream>>>(m2par, m2t);
    // t[q][j] = sum_i xb[q][i] * m2t[j][i]   (overwrites the partials slot)
    gemm_bf16<<<dim3(64, 8), 512, 0, stream>>>(xb, m2t, tb);
    // scores[b][q][k] = (t[q].x[k] + p[q] + r[k] + c0) / 512
    gemm_scores<<<dim3(8, 8, 8), 512, 0, stream>>>(tb, xb, pvec, rvec, c0, gout);
    softmax_kernel<<<8192, 256, 0, stream>>>(gout, adj, naout);
    cum2_kernel<<<8, 1024, 0, stream>>>(naout, prior, cumd);
    na_g_kernel<<<dim3(1024, 8), 256, 0, stream>>>(naout, prior, cumd, gout);
}

// Round 9
// 132.603 us; speedup vs baseline: 1.2994x; 1.0396x over previous
//
#include <hip/hip_runtime.h>
#include <hip/hip_bf16.h>

// Shapes (fixed for this problem)
#define S_LEN 1024
#define D_DIM 1024
#define N_BAT 8
#define BSS   (8ull*1024ull*1024ull)   // B*S*S elements per output

using bf16x8 = __attribute__((ext_vector_type(8))) short;
using f32x4  = __attribute__((ext_vector_type(4))) float;

__device__ __forceinline__ short f2bf(float v) {
    __hip_bfloat16 h = __float2bfloat16(v);
    return *reinterpret_cast<short*>(&h);
}

__device__ __forceinline__ void gload_lds16(const void* g, void* l) {
    __builtin_amdgcn_global_load_lds(
        (const __attribute__((address_space(1))) void*)g,
        (__attribute__((address_space(3))) void*)l, 16, 0, 0);
}

// ---------------------------------------------------------------------------
// 256x128-tile GEMM mainloop, BK=64, 8 waves (512 thr), wave tile 64x64
// (acc[4][4]) -> 2x better LDS-bytes/FLOP than 64x32. Ring-3 LDS
// (A 3x32KB + B 3x16KB = 144KB, 1 block/CU). Counted vmcnt(6): tile t+1
// stays in flight across the barrier; tile t+2 issued after ds_read.
// T2 XOR swizzle (pre-swizzled global source + same XOR on ds_read).
// T5 setprio around the MFMA cluster.
// ---------------------------------------------------------------------------
template<int KITERS>
__device__ __forceinline__ void gemm_mainloop256(
    const short* __restrict__ A, const short* __restrict__ Bt,
    int brow, int bcol, int kstart,
    short* As, short* Bs, f32x4 acc[4][4])
{
    const int tid  = threadIdx.x;
    const int lane = tid & 63;
    const int w    = tid >> 6;
    const int wr   = w >> 1;            // 0..3
    const int wc   = w & 1;             // 0..1
    const int rsel = lane & 15;
    const int kb   = (lane >> 4) * 16;  // byte offset of 16B k-chunk
    const int sw   = (rsel & 7) << 4;   // ds_read XOR (row&7 == rsel&7)

    // staging: chunk c covers rows c*64..c*64+63; per-thread row/col fixed
    const int srow  = tid >> 3;                              // 0..63
    const int scolb = ((tid & 7) * 16) ^ ((srow & 7) << 4);  // swizzled src byte
    const int sdst  = tid * 16;                              // linear LDS dest

#pragma unroll
    for (int m = 0; m < 4; ++m)
#pragma unroll
        for (int n = 0; n < 4; ++n) acc[m][n] = 0.0f;

    // ---- stage one K-tile (6 loads/thread: A x4, B x2) into ring slot ----
    auto stage = [&](int slot, int k0) {
        char* Ad = (char*)As + slot * 32768;
        char* Bd = (char*)Bs + slot * 16384;
#pragma unroll
        for (int c = 0; c < 4; ++c) {
            const int row = c * 64 + srow;
            gload_lds16((const char*)(A + (size_t)(brow + row) * 1024 + k0) + scolb,
                        Ad + c * 8192 + sdst);
        }
#pragma unroll
        for (int c = 0; c < 2; ++c) {
            const int row = c * 64 + srow;
            gload_lds16((const char*)(Bt + (size_t)(bcol + row) * 1024 + k0) + scolb,
                        Bd + c * 8192 + sdst);
        }
    };

    // prologue: tiles 0,1 into slots 0,1
    stage(0, kstart);
    if (KITERS > 1) stage(1, kstart + 64);

#pragma unroll
    for (int t = 0; t < KITERS; ++t) {
        // outstanding: tiles t,t+1 (12 loads) steady; tile t only (6) at tail
        if (t < KITERS - 1) asm volatile("s_waitcnt vmcnt(6)" ::: "memory");
        else                asm volatile("s_waitcnt vmcnt(0)" ::: "memory");
        __builtin_amdgcn_s_barrier();
        asm volatile("" ::: "memory");   // keep LDS reads below the barrier

        const char* Ac = (const char*)As + (t % 3) * 32768;
        const char* Bc = (const char*)Bs + (t % 3) * 16384;
        bf16x8 af[4][2], bfr[4][2];
#pragma unroll
        for (int m = 0; m < 4; ++m) {
            const int row = wr * 64 + m * 16 + rsel;
#pragma unroll
            for (int kk = 0; kk < 2; ++kk)
                af[m][kk] = *(const bf16x8*)&Ac[row * 128 + ((kk * 64 + kb) ^ sw)];
        }
#pragma unroll
        for (int n = 0; n < 4; ++n) {
            const int row = wc * 64 + n * 16 + rsel;
#pragma unroll
            for (int kk = 0; kk < 2; ++kk)
                bfr[n][kk] = *(const bf16x8*)&Bc[row * 128 + ((kk * 64 + kb) ^ sw)];
        }

        if (t + 2 < KITERS) stage((t + 2) % 3, kstart + (t + 2) * 64);

        __builtin_amdgcn_s_setprio(1);
#pragma unroll
        for (int kk = 0; kk < 2; ++kk)
#pragma unroll
            for (int m = 0; m < 4; ++m)
#pragma unroll
                for (int n = 0; n < 4; ++n)
                    acc[m][n] = __builtin_amdgcn_mfma_f32_16x16x32_bf16(
                        af[m][kk], bfr[n][kk], acc[m][n], 0, 0, 0);
        __builtin_amdgcn_s_setprio(0);
    }
}

// ---------------------------------------------------------------------------
// 3a) bf16-out GEMM for t = xb @ m2t^T. Grid (32, 8) = 256 blocks = 1/CU.
//     XCD map: 4 A-row-panels x all 8 cols per XCD (2MB A + 2MB B in L2).
// ---------------------------------------------------------------------------
__global__ __launch_bounds__(512) void gemm_bf16(
    const short* __restrict__ A, const short* __restrict__ Bt,
    short* __restrict__ C)
{
    __shared__ short As[3 * 16384];
    __shared__ short Bs[3 * 8192];
    const int flat = blockIdx.x + 32 * blockIdx.y;
    const int nid  = (flat & 7) * 32 + (flat >> 3);
    const int mx   = nid >> 3;          // 0..31
    const int ny   = nid & 7;           // 0..7
    const int brow = mx * 256, bcol = ny * 128;

    f32x4 acc[4][4];
    gemm_mainloop256<16>(A, Bt, brow, bcol, 0, As, Bs, acc);

    const int lane = threadIdx.x & 63;
    const int w    = threadIdx.x >> 6;
    const int wr   = w >> 1, wc = w & 1;
#pragma unroll
    for (int m = 0; m < 4; ++m)
#pragma unroll
        for (int n = 0; n < 4; ++n) {
            const int colg = bcol + wc * 64 + n * 16 + (lane & 15);
#pragma unroll
            for (int r = 0; r < 4; ++r) {
                const int rowg = brow + wr * 64 + m * 16 + ((lane >> 4) * 4 + r);
                C[(size_t)rowg * 1024 + colg] = f2bf(acc[m][n][r]);
            }
        }
}

// ---------------------------------------------------------------------------
// 3b) Scores GEMM (batched): Sc[b][q][k] = (t[q].x[k] + p[q] + r[k] + c0)/512
//     Grid (4,8,8) = 256 blocks = 1/CU; one batch per XCD (4MB in L2).
// ---------------------------------------------------------------------------
__global__ __launch_bounds__(512) void gemm_scores(
    const short* __restrict__ Tm, const short* __restrict__ Xm,
    const float* __restrict__ p, const float* __restrict__ r2,
    const float* __restrict__ c0p, float* __restrict__ Sc)
{
    __shared__ short As[3 * 16384];
    __shared__ short Bs[3 * 8192];
    const int flat = blockIdx.x + 4 * blockIdx.y + 32 * blockIdx.z;
    const int nid  = (flat & 7) * 32 + (flat >> 3);
    const int b    = nid >> 5;          // one batch per XCD
    const int rem  = nid & 31;
    const int mx   = rem & 3;           // 0..3
    const int ny   = rem >> 2;          // 0..7
    const short* A  = Tm + (size_t)b * 1024 * 1024;
    const short* Bt = Xm + (size_t)b * 1024 * 1024;
    const float* pb = p  + (size_t)b * 1024;
    const float* rb = r2 + (size_t)b * 1024;
    float* C = Sc + (size_t)b * 1024 * 1024;
    const int brow = mx * 256, bcol = ny * 128;

    f32x4 acc[4][4];
    gemm_mainloop256<16>(A, Bt, brow, bcol, 0, As, Bs, acc);

    const int lane = threadIdx.x & 63;
    const int w    = threadIdx.x >> 6;
    const int wr   = w >> 1, wc = w & 1;
    const float c0v = c0p[0];
#pragma unroll
    for (int m = 0; m < 4; ++m)
#pragma unroll
        for (int n = 0; n < 4; ++n) {
            const int colg = bcol + wc * 64 + n * 16 + (lane & 15);
            const float radd = rb[colg] + c0v;
#pragma unroll
            for (int r = 0; r < 4; ++r) {
                const int rowg = brow + wr * 64 + m * 16 + ((lane >> 4) * 4 + r);
                C[(size_t)rowg * 1024 + colg] =
                    (acc[m][n][r] + pb[rowg] + radd) * 0.001953125f; // /512
            }
        }
}

// ---------------------------------------------------------------------------
// 3c) M2T split-K GEMM: partial[z][j][i] = sum_{d in z-th 256} Wkt[j][d]Wqt[i][d]
//     Grid (4,8,4), KITERS=4.
// ---------------------------------------------------------------------------
__global__ __launch_bounds__(512) void gemm_splitk(
    const short* __restrict__ A, const short* __restrict__ Bt,
    float* __restrict__ P)
{
    __shared__ short As[3 * 16384];
    __shared__ short Bs[3 * 8192];
    const int brow = blockIdx.x * 256, bcol = blockIdx.y * 128;
    const int z = blockIdx.z;

    f32x4 acc[4][4];
    gemm_mainloop256<4>(A, Bt, brow, bcol, z * 256, As, Bs, acc);

    float* Pz = P + (size_t)z * 1024 * 1024;
    const int lane = threadIdx.x & 63;
    const int w    = threadIdx.x >> 6;
    const int wr   = w >> 1, wc = w & 1;
#pragma unroll
    for (int m = 0; m < 4; ++m)
#pragma unroll
        for (int n = 0; n < 4; ++n) {
            const int colg = bcol + wc * 64 + n * 16 + (lane & 15);
#pragma unroll
            for (int r = 0; r < 4; ++r) {
                const int rowg = brow + wr * 64 + m * 16 + ((lane >> 4) * 4 + r);
                Pz[(size_t)rowg * 1024 + colg] = acc[m][n][r];
            }
        }
}

// ---------------------------------------------------------------------------
// 3d) Reduce split-K partials -> bf16 m2t
// ---------------------------------------------------------------------------
__global__ __launch_bounds__(256) void reduce_m2t(
    const float* __restrict__ P, short* __restrict__ M)
{
    const int idx = blockIdx.x * 256 + threadIdx.x;   // float4 units
    const float4* P4 = (const float4*)P;
    float4 s = P4[idx];
    const float4 s1 = P4[idx + 262144];
    const float4 s2 = P4[idx + 524288];
    const float4 s3 = P4[idx + 786432];
    s.x += s1.x + s2.x + s3.x;
    s.y += s1.y + s2.y + s3.y;
    s.z += s1.z + s2.z + s3.z;
    s.w += s1.w + s2.w + s3.w;
    short4 o;
    o.x = f2bf(s.x); o.y = f2bf(s.y); o.z = f2bf(s.z); o.w = f2bf(s.w);
    ((short4*)M)[idx] = o;
}

// ---------------------------------------------------------------------------
// 0a) Bias GEMV stage 1: partial sums of u = Wq^T bk, v = Wk^T bq.
// ---------------------------------------------------------------------------
__global__ __launch_bounds__(256) void bias_gemv1(
    const float* __restrict__ Wq, const float* __restrict__ Wk,
    const float* __restrict__ bk, const float* __restrict__ bq,
    float* __restrict__ pu, float* __restrict__ pv)
{
    __shared__ float su[8][128];
    __shared__ float sv[8][128];
    const int tx = threadIdx.x & 31;
    const int ty = threadIdx.x >> 5;
    const int colBase = blockIdx.x * 128;
    const int rowBase = blockIdx.y * 64;
    const int i = colBase + tx * 4;
    float4 au = {0,0,0,0}, av = {0,0,0,0};
#pragma unroll
    for (int jj = 0; jj < 8; ++jj) {
        const int j = rowBase + ty + jj * 8;
        const float bkv = bk[j], bqv = bq[j];
        const float4 wq = *(const float4*)&Wq[(size_t)j * 1024 + i];
        const float4 wk = *(const float4*)&Wk[(size_t)j * 1024 + i];
        au.x += wq.x * bkv; au.y += wq.y * bkv; au.z += wq.z * bkv; au.w += wq.w * bkv;
        av.x += wk.x * bqv; av.y += wk.y * bqv; av.z += wk.z * bqv; av.w += wk.w * bqv;
    }
    ((float4*)su[ty])[tx] = au;
    ((float4*)sv[ty])[tx] = av;
    __syncthreads();
    if (ty == 0) {
        float4 s1 = ((float4*)su[0])[tx];
        float4 s2 = ((float4*)sv[0])[tx];
#pragma unroll
        for (int k = 1; k < 8; ++k) {
            const float4 t1 = ((float4*)su[k])[tx];
            const float4 t2 = ((float4*)sv[k])[tx];
            s1.x += t1.x; s1.y += t1.y; s1.z += t1.z; s1.w += t1.w;
            s2.x += t2.x; s2.y += t2.y; s2.z += t2.z; s2.w += t2.w;
        }
        ((float4*)&pu[(size_t)blockIdx.y * 1024 + colBase])[tx] = s1;
        ((float4*)&pv[(size_t)blockIdx.y * 1024 + colBase])[tx] = s2;
    }
}

// ---------------------------------------------------------------------------
// 0b) Bias GEMV stage 2: reduce 16 partials per column; also c0 = bq.bk
// ---------------------------------------------------------------------------
__global__ __launch_bounds__(256) void bias_gemv2(
    const float* __restrict__ pu, const float* __restrict__ pv,
    const float* __restrict__ bk, const float* __restrict__ bq,
    float* __restrict__ u, float* __restrict__ v, float* __restrict__ c0)
{
    __shared__ float sh[4];
    const int i = blockIdx.x * 256 + threadIdx.x;
    float su = 0.0f, sv = 0.0f;
#pragma unroll
    for (int k = 0; k < 16; ++k) {
        su += pu[k * 1024 + i];
        sv += pv[k * 1024 + i];
    }
    u[i] = su;
    v[i] = sv;
    if (blockIdx.x == 0) {
        const int t = threadIdx.x;
        const float4 a = ((const float4*)bq)[t];
        const float4 b = ((const float4*)bk)[t];
        float s = a.x*b.x + a.y*b.y + a.z*b.z + a.w*b.w;
        for (int off = 32; off > 0; off >>= 1) s += __shfl_down(s, off);
        const int lane = t & 63, w = t >> 6;
        if (lane == 0) sh[w] = s;
        __syncthreads();
        if (t == 0) c0[0] = sh[0] + sh[1] + sh[2] + sh[3];
    }
}

// ---------------------------------------------------------------------------
// 1) LayerNorm -> bf16; also emits p[row] = y.u and r2[row] = y.v
// ---------------------------------------------------------------------------
__global__ __launch_bounds__(256) void ln_kernel(
    const float* __restrict__ X, const float* __restrict__ gamma,
    const float* __restrict__ beta, const float* __restrict__ u,
    const float* __restrict__ v2, short* __restrict__ Y,
    float* __restrict__ p, float* __restrict__ r2)
{
    __shared__ float sh[16];
    const size_t row = blockIdx.x;
    const int t = threadIdx.x;
    float4 v = ((const float4*)(X + row * 1024))[t];
    float s  = v.x + v.y + v.z + v.w;
    float ss = v.x*v.x + v.y*v.y + v.z*v.z + v.w*v.w;
    for (int off = 32; off > 0; off >>= 1) {
        s  += __shfl_down(s, off);
        ss += __shfl_down(ss, off);
    }
    const int lane = t & 63, w = t >> 6;
    if (lane == 0) { sh[w] = s; sh[4 + w] = ss; }
    __syncthreads();
    if (t == 0) {
        float S  = sh[0] + sh[1] + sh[2] + sh[3];
        float SS = sh[4] + sh[5] + sh[6] + sh[7];
        float mu = S * (1.0f / 1024.0f);
        float var = fmaxf((SS - S * mu) * (1.0f / 1023.0f), 0.0f);
        sh[0] = mu;
        sh[1] = 1.0f / (sqrtf(var) + 1e-6f);
    }
    __syncthreads();
    const float mu = sh[0], inv = sh[1];
    float4 g  = ((const float4*)gamma)[t];
    float4 be = ((const float4*)beta)[t];
    float y0 = g.x * (v.x - mu) * inv + be.x;
    float y1 = g.y * (v.y - mu) * inv + be.y;
    float y2 = g.z * (v.z - mu) * inv + be.z;
    float y3 = g.w * (v.w - mu) * inv + be.w;
    short4 o;
    o.x = f2bf(y0); o.y = f2bf(y1); o.z = f2bf(y2); o.w = f2bf(y3);
    ((short4*)(Y + row * 1024))[t] = o;
    float4 uu = ((const float4*)u)[t];
    float4 vv = ((const float4*)v2)[t];
    float dp = y0*uu.x + y1*uu.y + y2*uu.z + y3*uu.w;
    float dr = y0*vv.x + y1*vv.y + y2*vv.z + y3*vv.w;
    for (int off = 32; off > 0; off >>= 1) {
        dp += __shfl_down(dp, off);
        dr += __shfl_down(dr, off);
    }
    if (lane == 0) { sh[8 + w] = dp; sh[12 + w] = dr; }
    __syncthreads();
    if (t == 0) {
        p[row]  = sh[8] + sh[9] + sh[10] + sh[11];
        r2[row] = sh[12] + sh[13] + sh[14] + sh[15];
    }
}

// ---------------------------------------------------------------------------
// 2) Transpose + convert Wq, Wk (f32 [D][D]) -> bf16 transposed copies
// ---------------------------------------------------------------------------
__global__ __launch_bounds__(256) void cvt_t_kernel(
    const float* __restrict__ Wq, const float* __restrict__ Wk,
    short* __restrict__ wqt, short* __restrict__ wkt)
{
    __shared__ float T[32][33];
    const float* src = blockIdx.z ? Wk : Wq;
    short* dst = blockIdx.z ? wkt : wqt;
    const int bi = blockIdx.x * 32, bj = blockIdx.y * 32;
    const int c = threadIdx.x & 31, r0 = threadIdx.x >> 5;
#pragma unroll
    for (int rr = 0; rr < 4; ++rr) {
        const int r = r0 + rr * 8;
        T[r][c] = src[(size_t)(bi + r) * 1024 + bj + c];
    }
    __syncthreads();
#pragma unroll
    for (int rr = 0; rr < 4; ++rr) {
        const int r = r0 + rr * 8;
        dst[(size_t)(bj + r) * 1024 + bi + c] = f2bf(T[c][r]);
    }
}

// ---------------------------------------------------------------------------
// 5) Masked row softmax: block per (b,q) row
// ---------------------------------------------------------------------------
__global__ __launch_bounds__(256) void softmax_kernel(
    const float* __restrict__ Sc, const int* __restrict__ adj,
    float* __restrict__ At)
{
    __shared__ float sh[4];
    const size_t row = blockIdx.x;
    const int t = threadIdx.x;
    const float4 sv = ((const float4*)(Sc + row * 1024))[t];
    const int4   av = ((const int4*)(adj + row * 1024))[t];
    float m = -3.0e38f;
    if (av.x) m = fmaxf(m, sv.x);
    if (av.y) m = fmaxf(m, sv.y);
    if (av.z) m = fmaxf(m, sv.z);
    if (av.w) m = fmaxf(m, sv.w);
    for (int off = 32; off > 0; off >>= 1) m = fmaxf(m, __shfl_down(m, off));
    const int lane = t & 63, w = t >> 6;
    if (lane == 0) sh[w] = m;
    __syncthreads();
    const float M = fmaxf(fmaxf(sh[0], sh[1]), fmaxf(sh[2], sh[3]));
    __syncthreads();
    float e0 = av.x ? expf(sv.x - M) : 0.0f;
    float e1 = av.y ? expf(sv.y - M) : 0.0f;
    float e2 = av.z ? expf(sv.z - M) : 0.0f;
    float e3 = av.w ? expf(sv.w - M) : 0.0f;
    float s = e0 + e1 + e2 + e3;
    for (int off = 32; off > 0; off >>= 1) s += __shfl_down(s, off);
    if (lane == 0) sh[w] = s;
    __syncthreads();
    const float Sm = sh[0] + sh[1] + sh[2] + sh[3];
    float4 o;
    if (Sm > 0.0f) {
        const float inv = 1.0f / Sm;
        o.x = e0 * inv; o.y = e1 * inv; o.z = e2 * inv; o.w = e3 * inv;
    } else {
        o.x = o.y = o.z = o.w = 1.0f / 1024.0f;
    }
    ((float4*)(At + row * 1024))[t] = o;
}

// ---------------------------------------------------------------------------
// 6) Prefix sums of L[k]=log(na[k,k+1]+1e-9) per batch (f64 scan in LDS)
// ---------------------------------------------------------------------------
__global__ __launch_bounds__(1024) void cum2_kernel(
    const float* __restrict__ At, const float* __restrict__ prior_p,
    double* __restrict__ cum)
{
    __shared__ double sh[1024];
    const int b = blockIdx.x;
    const int t = threadIdx.x;
    const float prior = *prior_p;
    const float om = 1.0f - prior;
    const float* attn = At + (size_t)b * 1024 * 1024;
    double v = 0.0;
    if (t >= 1) {
        const int k = t - 1;
        const float a1 = attn[(size_t)k * 1024 + (k + 1)];
        const float a2 = attn[(size_t)(k + 1) * 1024 + k];
        const float na = prior + om * sqrtf(a1 * a2 + 1e-9f);
        v = (double)logf(na + 1e-9f);
    }
    sh[t] = v;
    __syncthreads();
#pragma unroll
    for (int off = 1; off < 1024; off <<= 1) {
        const double add = (t >= off) ? sh[t - off] : 0.0;
        __syncthreads();
        sh[t] += add;
        __syncthreads();
    }
    cum[b * 1024 + t] = sh[t];
}

// ---------------------------------------------------------------------------
// 7) Fused na (in place) + g_attn fill. 32x32 tile-pair per block.
// ---------------------------------------------------------------------------
__global__ __launch_bounds__(256) void na_g_kernel(
    float* __restrict__ At, const float* __restrict__ prior_p,
    const double* __restrict__ cum, float* __restrict__ G)
{
    const int ti = blockIdx.x >> 5, tj = blockIdx.x & 31;
    if (tj < ti) return;
    const int b = blockIdx.y;
    const float prior = *prior_p;
    const float om = 1.0f - prior;
    float* base = At + (size_t)b * 1024 * 1024;
    float* gb   = G  + (size_t)b * 1024 * 1024;
    const double* cb = cum + (size_t)b * 1024;
    __shared__ float T1[32][33];
    __shared__ float T2[32][33];
    const int c = threadIdx.x & 31, r0 = threadIdx.x >> 5;
#pragma unroll
    for (int rr = 0; rr < 4; ++rr) {
        const int r = r0 + rr * 8;
        T1[r][c] = base[(size_t)(ti * 32 + r) * 1024 + tj * 32 + c];
        T2[r][c] = base[(size_t)(tj * 32 + r) * 1024 + ti * 32 + c];
    }
    __syncthreads();
#pragma unroll
    for (int rr = 0; rr < 4; ++rr) {
        const int r = r0 + rr * 8;
        const int R1 = ti * 32 + r, C1 = tj * 32 + c;
        const float na1 = prior + om * sqrtf(T1[r][c] * T2[c][r] + 1e-9f);
        base[(size_t)R1 * 1024 + C1] = na1;
        float g1;
        if (R1 == C1) g1 = na1;
        else {
            const int lo = min(R1, C1), hi = max(R1, C1);
            g1 = expf((float)(cb[hi] - cb[lo])) + 1e-9f;
        }
        gb[(size_t)R1 * 1024 + C1] = g1;
        const int R2 = tj * 32 + r, C2 = ti * 32 + c;
        const float na2 = prior + om * sqrtf(T2[r][c] * T1[c][r] + 1e-9f);
        base[(size_t)R2 * 1024 + C2] = na2;
        float g2;
        if (R2 == C2) g2 = na2;
        else {
            const int lo = min(R2, C2), hi = max(R2, C2);
            g2 = expf((float)(cb[hi] - cb[lo])) + 1e-9f;
        }
        gb[(size_t)R2 * 1024 + C2] = g2;
    }
}

// ---------------------------------------------------------------------------
extern "C" void kernel_launch(void* const* d_in, const int* in_sizes, int n_in,
                              void* d_out, int out_size, void* d_ws, size_t ws_size,
                              hipStream_t stream)
{
    const float* context = (const float*)d_in[0];
    // d_in[1] = eos_mask (unused by reference)
    const float* prior   = (const float*)d_in[2];
    const int*   adj     = (const int*)d_in[3];
    const float* Wk      = (const float*)d_in[4];
    const float* bk      = (const float*)d_in[5];
    const float* Wq      = (const float*)d_in[6];
    const float* bq      = (const float*)d_in[7];
    const float* gamma   = (const float*)d_in[8];
    const float* beta    = (const float*)d_in[9];

    float* out   = (float*)d_out;
    float* gout  = out;          // first output: g_attn (scores scratch first)
    float* naout = out + BSS;    // second output: neibor_attn (attn in-place)

    // workspace layout (~39 MB)
    char* ws = (char*)d_ws;
    short*  xb    = (short*)(ws);                        // 16 MB  x (bf16)
    short*  wqt   = (short*)(ws + (16ull << 20));        //  2 MB  Wq^T (bf16)
    short*  wkt   = (short*)(ws + (18ull << 20));        //  2 MB  Wk^T (bf16)
    short*  m2t   = (short*)(ws + (20ull << 20));        //  2 MB  (Wq^T Wk)^T
    short*  tb    = (short*)(ws + (22ull << 20));        // 16 MB  t = x@M2
    float*  m2par = (float*)tb;                          // 16 MB  split-K partials (aliased; consumed before tb written)
    double* cumd  = (double*)(ws + (38ull << 20));       // 64 KB
    float*  uvec  = (float*)(ws + (38ull << 20) + (1ull << 16)); // 4 KB
    float*  vvec  = uvec + 1024;                         // 4 KB
    float*  c0    = vvec + 1024;                         // 4 B (padded)
    float*  pvec  = c0 + 64;                             // 32 KB (8192 f32)
    float*  rvec  = pvec + 8192;                         // 32 KB
    float*  pu    = rvec + 8192;                         // 64 KB (16x1024)
    float*  pv    = pu + 16384;                          // 64 KB

    bias_gemv1<<<dim3(8, 16), 256, 0, stream>>>(Wq, Wk, bk, bq, pu, pv);
    bias_gemv2<<<4, 256, 0, stream>>>(pu, pv, bk, bq, uvec, vvec, c0);
    ln_kernel<<<8192, 256, 0, stream>>>(context, gamma, beta, uvec, vvec,
                                        xb, pvec, rvec);
    cvt_t_kernel<<<dim3(32, 32, 2), 256, 0, stream>>>(Wq, Wk, wqt, wkt);
    // M2T[j][i] = sum_d Wkt[j][d] * Wqt[i][d], split-K x4 + reduce
    gemm_splitk<<<dim3(4, 8, 4), 512, 0, stream>>>(wkt, wqt, m2par);
    reduce_m2t<<<1024, 256, 0, stream>>>(m2par, m2t);
    // t[q][j] = sum_i xb[q][i] * m2t[j][i]   (overwrites the partials slot)
    gemm_bf16<<<dim3(32, 8), 512, 0, stream>>>(xb, m2t, tb);
    // scores[b][q][k] = (t[q].x[k] + p[q] + r[k] + c0) / 512
    gemm_scores<<<dim3(4, 8, 8), 512, 0, stream>>>(tb, xb, pvec, rvec, c0, gout);
    softmax_kernel<<<8192, 256, 0, stream>>>(gout, adj, naout);
    cum2_kernel<<<8, 1024, 0, stream>>>(naout, prior, cumd);
    na_g_kernel<<<dim3(1024, 8), 256, 0, stream>>>(naout, prior, cumd, gout);
}

// Round 10
// 123.162 us; speedup vs baseline: 1.3990x; 1.0767x over previous
//
#include <hip/hip_runtime.h>
#include <hip/hip_bf16.h>

// Shapes (fixed for this problem)
#define S_LEN 1024
#define D_DIM 1024
#define N_BAT 8
#define BSS   (8ull*1024ull*1024ull)   // B*S*S elements per output

using bf16x8 = __attribute__((ext_vector_type(8))) short;
using f32x4  = __attribute__((ext_vector_type(4))) float;

__device__ __forceinline__ short f2bf(float v) {
    __hip_bfloat16 h = __float2bfloat16(v);
    return *reinterpret_cast<short*>(&h);
}

__device__ __forceinline__ void gload_lds16(const void* g, void* l) {
    __builtin_amdgcn_global_load_lds(
        (const __attribute__((address_space(1))) void*)g,
        (__attribute__((address_space(3))) void*)l, 16, 0, 0);
}

// ---------------------------------------------------------------------------
// 256x128-tile GEMM mainloop, BK=64, 8 waves (512 thr), wave tile 64x64.
// Ring-3 LDS; counted vmcnt(6); T2 XOR swizzle; T5 setprio. (unchanged R9)
// ---------------------------------------------------------------------------
template<int KITERS>
__device__ __forceinline__ void gemm_mainloop256(
    const short* __restrict__ A, const short* __restrict__ Bt,
    int brow, int bcol, int kstart,
    short* As, short* Bs, f32x4 acc[4][4])
{
    const int tid  = threadIdx.x;
    const int lane = tid & 63;
    const int w    = tid >> 6;
    const int wr   = w >> 1;            // 0..3
    const int wc   = w & 1;             // 0..1
    const int rsel = lane & 15;
    const int kb   = (lane >> 4) * 16;
    const int sw   = (rsel & 7) << 4;

    const int srow  = tid >> 3;                              // 0..63
    const int scolb = ((tid & 7) * 16) ^ ((srow & 7) << 4);  // swizzled src byte
    const int sdst  = tid * 16;                              // linear LDS dest

#pragma unroll
    for (int m = 0; m < 4; ++m)
#pragma unroll
        for (int n = 0; n < 4; ++n) acc[m][n] = 0.0f;

    auto stage = [&](int slot, int k0) {
        char* Ad = (char*)As + slot * 32768;
        char* Bd = (char*)Bs + slot * 16384;
#pragma unroll
        for (int c = 0; c < 4; ++c) {
            const int row = c * 64 + srow;
            gload_lds16((const char*)(A + (size_t)(brow + row) * 1024 + k0) + scolb,
                        Ad + c * 8192 + sdst);
        }
#pragma unroll
        for (int c = 0; c < 2; ++c) {
            const int row = c * 64 + srow;
            gload_lds16((const char*)(Bt + (size_t)(bcol + row) * 1024 + k0) + scolb,
                        Bd + c * 8192 + sdst);
        }
    };

    stage(0, kstart);
    if (KITERS > 1) stage(1, kstart + 64);

#pragma unroll
    for (int t = 0; t < KITERS; ++t) {
        if (t < KITERS - 1) asm volatile("s_waitcnt vmcnt(6)" ::: "memory");
        else                asm volatile("s_waitcnt vmcnt(0)" ::: "memory");
        __builtin_amdgcn_s_barrier();
        asm volatile("" ::: "memory");

        const char* Ac = (const char*)As + (t % 3) * 32768;
        const char* Bc = (const char*)Bs + (t % 3) * 16384;
        bf16x8 af[4][2], bfr[4][2];
#pragma unroll
        for (int m = 0; m < 4; ++m) {
            const int row = wr * 64 + m * 16 + rsel;
#pragma unroll
            for (int kk = 0; kk < 2; ++kk)
                af[m][kk] = *(const bf16x8*)&Ac[row * 128 + ((kk * 64 + kb) ^ sw)];
        }
#pragma unroll
        for (int n = 0; n < 4; ++n) {
            const int row = wc * 64 + n * 16 + rsel;
#pragma unroll
            for (int kk = 0; kk < 2; ++kk)
                bfr[n][kk] = *(const bf16x8*)&Bc[row * 128 + ((kk * 64 + kb) ^ sw)];
        }

        if (t + 2 < KITERS) stage((t + 2) % 3, kstart + (t + 2) * 64);

        __builtin_amdgcn_s_setprio(1);
#pragma unroll
        for (int kk = 0; kk < 2; ++kk)
#pragma unroll
            for (int m = 0; m < 4; ++m)
#pragma unroll
                for (int n = 0; n < 4; ++n)
                    acc[m][n] = __builtin_amdgcn_mfma_f32_16x16x32_bf16(
                        af[m][kk], bfr[n][kk], acc[m][n], 0, 0, 0);
        __builtin_amdgcn_s_setprio(0);
    }
}

// ---------------------------------------------------------------------------
// 3a) bf16-out GEMM for t = xb @ m2t^T. Grid (32, 8) = 256 blocks.
// ---------------------------------------------------------------------------
__global__ __launch_bounds__(512) void gemm_bf16(
    const short* __restrict__ A, const short* __restrict__ Bt,
    short* __restrict__ C)
{
    __shared__ short As[3 * 16384];
    __shared__ short Bs[3 * 8192];
    const int flat = blockIdx.x + 32 * blockIdx.y;
    const int nid  = (flat & 7) * 32 + (flat >> 3);
    const int mx   = nid >> 3;
    const int ny   = nid & 7;
    const int brow = mx * 256, bcol = ny * 128;

    f32x4 acc[4][4];
    gemm_mainloop256<16>(A, Bt, brow, bcol, 0, As, Bs, acc);

    const int lane = threadIdx.x & 63;
    const int w    = threadIdx.x >> 6;
    const int wr   = w >> 1, wc = w & 1;
#pragma unroll
    for (int m = 0; m < 4; ++m)
#pragma unroll
        for (int n = 0; n < 4; ++n) {
            const int colg = bcol + wc * 64 + n * 16 + (lane & 15);
#pragma unroll
            for (int r = 0; r < 4; ++r) {
                const int rowg = brow + wr * 64 + m * 16 + ((lane >> 4) * 4 + r);
                C[(size_t)rowg * 1024 + colg] = f2bf(acc[m][n][r]);
            }
        }
}

// ---------------------------------------------------------------------------
// 3b) Scores GEMM + MASK fused epilogue:
//     Sc[b][q][k] = adj ? (t[q].x[k] + p[q] + r[k] + c0)/512 : -1e9
//     Grid (4,8,8); one batch per XCD.
// ---------------------------------------------------------------------------
__global__ __launch_bounds__(512) void gemm_scores(
    const short* __restrict__ Tm, const short* __restrict__ Xm,
    const float* __restrict__ p, const float* __restrict__ r2,
    const float* __restrict__ c0p, const int* __restrict__ adj,
    float* __restrict__ Sc)
{
    __shared__ short As[3 * 16384];
    __shared__ short Bs[3 * 8192];
    const int flat = blockIdx.x + 4 * blockIdx.y + 32 * blockIdx.z;
    const int nid  = (flat & 7) * 32 + (flat >> 3);
    const int b    = nid >> 5;
    const int rem  = nid & 31;
    const int mx   = rem & 3;
    const int ny   = rem >> 2;
    const short* A  = Tm + (size_t)b * 1024 * 1024;
    const short* Bt = Xm + (size_t)b * 1024 * 1024;
    const float* pb = p  + (size_t)b * 1024;
    const float* rb = r2 + (size_t)b * 1024;
    const int*   ab = adj + (size_t)b * 1024 * 1024;
    float* C = Sc + (size_t)b * 1024 * 1024;
    const int brow = mx * 256, bcol = ny * 128;

    f32x4 acc[4][4];
    gemm_mainloop256<16>(A, Bt, brow, bcol, 0, As, Bs, acc);

    const int lane = threadIdx.x & 63;
    const int w    = threadIdx.x >> 6;
    const int wr   = w >> 1, wc = w & 1;
    const float c0v = c0p[0];
#pragma unroll
    for (int m = 0; m < 4; ++m)
#pragma unroll
        for (int n = 0; n < 4; ++n) {
            const int colg = bcol + wc * 64 + n * 16 + (lane & 15);
            const float radd = rb[colg] + c0v;
#pragma unroll
            for (int r = 0; r < 4; ++r) {
                const int rowg = brow + wr * 64 + m * 16 + ((lane >> 4) * 4 + r);
                const size_t idx = (size_t)rowg * 1024 + colg;
                const float val = (acc[m][n][r] + pb[rowg] + radd) * 0.001953125f;
                C[idx] = ab[idx] ? val : -1e9f;   // reference's exact mask value
            }
        }
}

// ---------------------------------------------------------------------------
// 3c) M2T split-K GEMM (grid (4,8,4), KITERS=4)
// ---------------------------------------------------------------------------
__global__ __launch_bounds__(512) void gemm_splitk(
    const short* __restrict__ A, const short* __restrict__ Bt,
    float* __restrict__ P)
{
    __shared__ short As[3 * 16384];
    __shared__ short Bs[3 * 8192];
    const int brow = blockIdx.x * 256, bcol = blockIdx.y * 128;
    const int z = blockIdx.z;

    f32x4 acc[4][4];
    gemm_mainloop256<4>(A, Bt, brow, bcol, z * 256, As, Bs, acc);

    float* Pz = P + (size_t)z * 1024 * 1024;
    const int lane = threadIdx.x & 63;
    const int w    = threadIdx.x >> 6;
    const int wr   = w >> 1, wc = w & 1;
#pragma unroll
    for (int m = 0; m < 4; ++m)
#pragma unroll
        for (int n = 0; n < 4; ++n) {
            const int colg = bcol + wc * 64 + n * 16 + (lane & 15);
#pragma unroll
            for (int r = 0; r < 4; ++r) {
                const int rowg = brow + wr * 64 + m * 16 + ((lane >> 4) * 4 + r);
                Pz[(size_t)rowg * 1024 + colg] = acc[m][n][r];
            }
        }
}

// ---------------------------------------------------------------------------
// 3d) Reduce split-K partials -> bf16 m2t
// ---------------------------------------------------------------------------
__global__ __launch_bounds__(256) void reduce_m2t(
    const float* __restrict__ P, short* __restrict__ M)
{
    const int idx = blockIdx.x * 256 + threadIdx.x;
    const float4* P4 = (const float4*)P;
    float4 s = P4[idx];
    const float4 s1 = P4[idx + 262144];
    const float4 s2 = P4[idx + 524288];
    const float4 s3 = P4[idx + 786432];
    s.x += s1.x + s2.x + s3.x;
    s.y += s1.y + s2.y + s3.y;
    s.z += s1.z + s2.z + s3.z;
    s.w += s1.w + s2.w + s3.w;
    short4 o;
    o.x = f2bf(s.x); o.y = f2bf(s.y); o.z = f2bf(s.z); o.w = f2bf(s.w);
    ((short4*)M)[idx] = o;
}

// ---------------------------------------------------------------------------
// 0a/0b) Bias GEMV (unchanged)
// ---------------------------------------------------------------------------
__global__ __launch_bounds__(256) void bias_gemv1(
    const float* __restrict__ Wq, const float* __restrict__ Wk,
    const float* __restrict__ bk, const float* __restrict__ bq,
    float* __restrict__ pu, float* __restrict__ pv)
{
    __shared__ float su[8][128];
    __shared__ float sv[8][128];
    const int tx = threadIdx.x & 31;
    const int ty = threadIdx.x >> 5;
    const int colBase = blockIdx.x * 128;
    const int rowBase = blockIdx.y * 64;
    const int i = colBase + tx * 4;
    float4 au = {0,0,0,0}, av = {0,0,0,0};
#pragma unroll
    for (int jj = 0; jj < 8; ++jj) {
        const int j = rowBase + ty + jj * 8;
        const float bkv = bk[j], bqv = bq[j];
        const float4 wq = *(const float4*)&Wq[(size_t)j * 1024 + i];
        const float4 wk = *(const float4*)&Wk[(size_t)j * 1024 + i];
        au.x += wq.x * bkv; au.y += wq.y * bkv; au.z += wq.z * bkv; au.w += wq.w * bkv;
        av.x += wk.x * bqv; av.y += wk.y * bqv; av.z += wk.z * bqv; av.w += wk.w * bqv;
    }
    ((float4*)su[ty])[tx] = au;
    ((float4*)sv[ty])[tx] = av;
    __syncthreads();
    if (ty == 0) {
        float4 s1 = ((float4*)su[0])[tx];
        float4 s2 = ((float4*)sv[0])[tx];
#pragma unroll
        for (int k = 1; k < 8; ++k) {
            const float4 t1 = ((float4*)su[k])[tx];
            const float4 t2 = ((float4*)sv[k])[tx];
            s1.x += t1.x; s1.y += t1.y; s1.z += t1.z; s1.w += t1.w;
            s2.x += t2.x; s2.y += t2.y; s2.z += t2.z; s2.w += t2.w;
        }
        ((float4*)&pu[(size_t)blockIdx.y * 1024 + colBase])[tx] = s1;
        ((float4*)&pv[(size_t)blockIdx.y * 1024 + colBase])[tx] = s2;
    }
}

__global__ __launch_bounds__(256) void bias_gemv2(
    const float* __restrict__ pu, const float* __restrict__ pv,
    const float* __restrict__ bk, const float* __restrict__ bq,
    float* __restrict__ u, float* __restrict__ v, float* __restrict__ c0)
{
    __shared__ float sh[4];
    const int i = blockIdx.x * 256 + threadIdx.x;
    float su = 0.0f, sv = 0.0f;
#pragma unroll
    for (int k = 0; k < 16; ++k) {
        su += pu[k * 1024 + i];
        sv += pv[k * 1024 + i];
    }
    u[i] = su;
    v[i] = sv;
    if (blockIdx.x == 0) {
        const int t = threadIdx.x;
        const float4 a = ((const float4*)bq)[t];
        const float4 b = ((const float4*)bk)[t];
        float s = a.x*b.x + a.y*b.y + a.z*b.z + a.w*b.w;
        for (int off = 32; off > 0; off >>= 1) s += __shfl_down(s, off);
        const int lane = t & 63, w = t >> 6;
        if (lane == 0) sh[w] = s;
        __syncthreads();
        if (t == 0) c0[0] = sh[0] + sh[1] + sh[2] + sh[3];
    }
}

// ---------------------------------------------------------------------------
// 1) LayerNorm -> bf16 (unchanged)
// ---------------------------------------------------------------------------
__global__ __launch_bounds__(256) void ln_kernel(
    const float* __restrict__ X, const float* __restrict__ gamma,
    const float* __restrict__ beta, const float* __restrict__ u,
    const float* __restrict__ v2, short* __restrict__ Y,
    float* __restrict__ p, float* __restrict__ r2)
{
    __shared__ float sh[16];
    const size_t row = blockIdx.x;
    const int t = threadIdx.x;
    float4 v = ((const float4*)(X + row * 1024))[t];
    float s  = v.x + v.y + v.z + v.w;
    float ss = v.x*v.x + v.y*v.y + v.z*v.z + v.w*v.w;
    for (int off = 32; off > 0; off >>= 1) {
        s  += __shfl_down(s, off);
        ss += __shfl_down(ss, off);
    }
    const int lane = t & 63, w = t >> 6;
    if (lane == 0) { sh[w] = s; sh[4 + w] = ss; }
    __syncthreads();
    if (t == 0) {
        float S  = sh[0] + sh[1] + sh[2] + sh[3];
        float SS = sh[4] + sh[5] + sh[6] + sh[7];
        float mu = S * (1.0f / 1024.0f);
        float var = fmaxf((SS - S * mu) * (1.0f / 1023.0f), 0.0f);
        sh[0] = mu;
        sh[1] = 1.0f / (sqrtf(var) + 1e-6f);
    }
    __syncthreads();
    const float mu = sh[0], inv = sh[1];
    float4 g  = ((const float4*)gamma)[t];
    float4 be = ((const float4*)beta)[t];
    float y0 = g.x * (v.x - mu) * inv + be.x;
    float y1 = g.y * (v.y - mu) * inv + be.y;
    float y2 = g.z * (v.z - mu) * inv + be.z;
    float y3 = g.w * (v.w - mu) * inv + be.w;
    short4 o;
    o.x = f2bf(y0); o.y = f2bf(y1); o.z = f2bf(y2); o.w = f2bf(y3);
    ((short4*)(Y + row * 1024))[t] = o;
    float4 uu = ((const float4*)u)[t];
    float4 vv = ((const float4*)v2)[t];
    float dp = y0*uu.x + y1*uu.y + y2*uu.z + y3*uu.w;
    float dr = y0*vv.x + y1*vv.y + y2*vv.z + y3*vv.w;
    for (int off = 32; off > 0; off >>= 1) {
        dp += __shfl_down(dp, off);
        dr += __shfl_down(dr, off);
    }
    if (lane == 0) { sh[8 + w] = dp; sh[12 + w] = dr; }
    __syncthreads();
    if (t == 0) {
        p[row]  = sh[8] + sh[9] + sh[10] + sh[11];
        r2[row] = sh[12] + sh[13] + sh[14] + sh[15];
    }
}

// ---------------------------------------------------------------------------
// 2) Transpose + convert Wq, Wk -> bf16 transposed copies (unchanged)
// ---------------------------------------------------------------------------
__global__ __launch_bounds__(256) void cvt_t_kernel(
    const float* __restrict__ Wq, const float* __restrict__ Wk,
    short* __restrict__ wqt, short* __restrict__ wkt)
{
    __shared__ float T[32][33];
    const float* src = blockIdx.z ? Wk : Wq;
    short* dst = blockIdx.z ? wkt : wqt;
    const int bi = blockIdx.x * 32, bj = blockIdx.y * 32;
    const int c = threadIdx.x & 31, r0 = threadIdx.x >> 5;
#pragma unroll
    for (int rr = 0; rr < 4; ++rr) {
        const int r = r0 + rr * 8;
        T[r][c] = src[(size_t)(bi + r) * 1024 + bj + c];
    }
    __syncthreads();
#pragma unroll
    for (int rr = 0; rr < 4; ++rr) {
        const int r = r0 + rr * 8;
        dst[(size_t)(bj + r) * 1024 + bi + c] = f2bf(T[c][r]);
    }
}

// ---------------------------------------------------------------------------
// 5) Row stats: M = rowmax(masked scores), inv = 1/sum(exp(sc-M)).
//    Masked entries are -1e9 -> exp underflows to 0; all-masked row ->
//    M=-1e9, every exp=1, S=1024 -> uniform 1/1024 (matches jax exactly).
// ---------------------------------------------------------------------------
__global__ __launch_bounds__(256) void rowstat_kernel(
    const float* __restrict__ Sc, float2* __restrict__ stats)
{
    __shared__ float sh[4];
    const size_t row = blockIdx.x;
    const int t = threadIdx.x;
    const float4 sv = ((const float4*)(Sc + row * 1024))[t];
    float m = fmaxf(fmaxf(sv.x, sv.y), fmaxf(sv.z, sv.w));
    for (int off = 32; off > 0; off >>= 1) m = fmaxf(m, __shfl_down(m, off));
    const int lane = t & 63, w = t >> 6;
    if (lane == 0) sh[w] = m;
    __syncthreads();
    const float M = fmaxf(fmaxf(sh[0], sh[1]), fmaxf(sh[2], sh[3]));
    __syncthreads();
    float s = expf(sv.x - M) + expf(sv.y - M) + expf(sv.z - M) + expf(sv.w - M);
    for (int off = 32; off > 0; off >>= 1) s += __shfl_down(s, off);
    if (lane == 0) sh[w] = s;
    __syncthreads();
    if (t == 0) {
        const float Sm = sh[0] + sh[1] + sh[2] + sh[3];
        stats[row] = make_float2(M, 1.0f / Sm);
    }
}

// ---------------------------------------------------------------------------
// 6) Prefix sums of L[k]=log(na[k,k+1]+1e-9) per batch, attn recomputed
//    from masked scores + row stats. f64 Hillis-Steele scan in LDS.
// ---------------------------------------------------------------------------
__global__ __launch_bounds__(1024) void cum2_kernel(
    const float* __restrict__ Sc, const float2* __restrict__ stats,
    const float* __restrict__ prior_p, double* __restrict__ cum)
{
    __shared__ double sh[1024];
    const int b = blockIdx.x;
    const int t = threadIdx.x;
    const float prior = *prior_p;
    const float om = 1.0f - prior;
    const float* sc = Sc + (size_t)b * 1024 * 1024;
    const float2* st = stats + (size_t)b * 1024;
    double v = 0.0;
    if (t >= 1) {
        const int k = t - 1;
        const float2 s1 = st[k], s2 = st[k + 1];
        const float a1 = expf(sc[(size_t)k * 1024 + (k + 1)] - s1.x) * s1.y;
        const float a2 = expf(sc[(size_t)(k + 1) * 1024 + k] - s2.x) * s2.y;
        const float na = prior + om * sqrtf(a1 * a2 + 1e-9f);
        v = (double)logf(na + 1e-9f);
    }
    sh[t] = v;
    __syncthreads();
#pragma unroll
    for (int off = 1; off < 1024; off <<= 1) {
        const double add = (t >= off) ? sh[t - off] : 0.0;
        __syncthreads();
        sh[t] += add;
        __syncthreads();
    }
    cum[b * 1024 + t] = sh[t];
}

// ---------------------------------------------------------------------------
// 7) Fused softmax-finish + na + g fill. 32x32 tile-pair per block.
//    Reads masked score tiles (L2-resident per XCD) + stats, computes attn
//    on the fly, writes na -> NA output and g -> G output (G overwrites
//    the scores buffer in place; both tiles LDS-staged before any write).
//    Grid (1024, 8); bijective remap puts batch b on XCD b for L2 reuse.
// ---------------------------------------------------------------------------
__global__ __launch_bounds__(256) void na_g2_kernel(
    float* __restrict__ Sc, const float2* __restrict__ stats,
    const float* __restrict__ prior_p, const double* __restrict__ cum,
    float* __restrict__ NA)
{
    const int flat = blockIdx.x + 1024 * blockIdx.y;
    const int nid  = (flat & 7) * 1024 + (flat >> 3);
    const int b    = nid >> 10;
    const int tidx = nid & 1023;
    const int ti = tidx >> 5, tj = tidx & 31;
    if (tj < ti) return;
    const float prior = *prior_p;
    const float om = 1.0f - prior;
    float* sc = Sc + (size_t)b * 1024 * 1024;      // scores in, g out
    float* na = NA + (size_t)b * 1024 * 1024;
    const float2* st = stats + (size_t)b * 1024;
    const double* cb = cum + (size_t)b * 1024;
    __shared__ float T1[32][33];
    __shared__ float T2[32][33];
    const int c = threadIdx.x & 31, r0 = threadIdx.x >> 5;
#pragma unroll
    for (int rr = 0; rr < 4; ++rr) {
        const int r = r0 + rr * 8;
        const int R1 = ti * 32 + r, R2 = tj * 32 + r;
        const float2 s1 = st[R1], s2 = st[R2];
        T1[r][c] = expf(sc[(size_t)R1 * 1024 + tj * 32 + c] - s1.x) * s1.y;
        T2[r][c] = expf(sc[(size_t)R2 * 1024 + ti * 32 + c] - s2.x) * s2.y;
    }
    __syncthreads();
#pragma unroll
    for (int rr = 0; rr < 4; ++rr) {
        const int r = r0 + rr * 8;
        const int R1 = ti * 32 + r, C1 = tj * 32 + c;
        const float na1 = prior + om * sqrtf(T1[r][c] * T2[c][r] + 1e-9f);
        na[(size_t)R1 * 1024 + C1] = na1;
        float g1;
        if (R1 == C1) g1 = na1;
        else {
            const int lo = min(R1, C1), hi = max(R1, C1);
            g1 = expf((float)(cb[hi] - cb[lo])) + 1e-9f;
        }
        sc[(size_t)R1 * 1024 + C1] = g1;
        const int R2 = tj * 32 + r, C2 = ti * 32 + c;
        const float na2 = prior + om * sqrtf(T2[r][c] * T1[c][r] + 1e-9f);
        na[(size_t)R2 * 1024 + C2] = na2;
        float g2;
        if (R2 == C2) g2 = na2;
        else {
            const int lo = min(R2, C2), hi = max(R2, C2);
            g2 = expf((float)(cb[hi] - cb[lo])) + 1e-9f;
        }
        sc[(size_t)R2 * 1024 + C2] = g2;
    }
}

// ---------------------------------------------------------------------------
extern "C" void kernel_launch(void* const* d_in, const int* in_sizes, int n_in,
                              void* d_out, int out_size, void* d_ws, size_t ws_size,
                              hipStream_t stream)
{
    const float* context = (const float*)d_in[0];
    // d_in[1] = eos_mask (unused by reference)
    const float* prior   = (const float*)d_in[2];
    const int*   adj     = (const int*)d_in[3];
    const float* Wk      = (const float*)d_in[4];
    const float* bk      = (const float*)d_in[5];
    const float* Wq      = (const float*)d_in[6];
    const float* bq      = (const float*)d_in[7];
    const float* gamma   = (const float*)d_in[8];
    const float* beta    = (const float*)d_in[9];

    float* out   = (float*)d_out;
    float* gout  = out;          // g_attn output (holds masked scores first)
    float* naout = out + BSS;    // neibor_attn output

    // workspace layout (~39 MB)
    char* ws = (char*)d_ws;
    short*  xb    = (short*)(ws);                        // 16 MB  x (bf16)
    short*  wqt   = (short*)(ws + (16ull << 20));        //  2 MB  Wq^T (bf16)
    short*  wkt   = (short*)(ws + (18ull << 20));        //  2 MB  Wk^T (bf16)
    short*  m2t   = (short*)(ws + (20ull << 20));        //  2 MB  (Wq^T Wk)^T
    short*  tb    = (short*)(ws + (22ull << 20));        // 16 MB  t = x@M2
    float*  m2par = (float*)tb;                          // 16 MB  split-K partials (aliased)
    double* cumd  = (double*)(ws + (38ull << 20));       // 64 KB
    float*  uvec  = (float*)(ws + (38ull << 20) + (1ull << 16)); // 4 KB
    float*  vvec  = uvec + 1024;                         // 4 KB
    float*  c0    = vvec + 1024;                         // 4 B (padded)
    float*  pvec  = c0 + 64;                             // 32 KB (8192 f32)
    float*  rvec  = pvec + 8192;                         // 32 KB
    float*  pu    = rvec + 8192;                         // 64 KB (16x1024)
    float*  pv    = pu + 16384;                          // 64 KB
    float2* statv = (float2*)(pv + 16384);               // 64 KB (8192 float2)

    bias_gemv1<<<dim3(8, 16), 256, 0, stream>>>(Wq, Wk, bk, bq, pu, pv);
    bias_gemv2<<<4, 256, 0, stream>>>(pu, pv, bk, bq, uvec, vvec, c0);
    ln_kernel<<<8192, 256, 0, stream>>>(context, gamma, beta, uvec, vvec,
                                        xb, pvec, rvec);
    cvt_t_kernel<<<dim3(32, 32, 2), 256, 0, stream>>>(Wq, Wk, wqt, wkt);
    gemm_splitk<<<dim3(4, 8, 4), 512, 0, stream>>>(wkt, wqt, m2par);
    reduce_m2t<<<1024, 256, 0, stream>>>(m2par, m2t);
    gemm_bf16<<<dim3(32, 8), 512, 0, stream>>>(xb, m2t, tb);
    // masked scores -> gout
    gemm_scores<<<dim3(4, 8, 8), 512, 0, stream>>>(tb, xb, pvec, rvec, c0,
                                                   adj, gout);
    rowstat_kernel<<<8192, 256, 0, stream>>>(gout, statv);
    cum2_kernel<<<8, 1024, 0, stream>>>(gout, statv, prior, cumd);
    na_g2_kernel<<<dim3(1024, 8), 256, 0, stream>>>(gout, statv, prior, cumd,
                                                    naout);
}